// Round 10
// baseline (1414.252 us; speedup 1.0000x reference)
//
#include <hip/hip_runtime.h>
#include <hip/hip_bf16.h>

typedef __attribute__((ext_vector_type(8))) short bf16x8;
typedef __attribute__((ext_vector_type(4))) float f32x4;

#define TILE 64
#define TK 16

__device__ inline short f2bf(float x) {
    unsigned u = __float_as_uint(x);
    unsigned r = (u + 0x7fffu + ((u >> 16) & 1u)) >> 16;
    return (short)r;
}
__device__ inline float bf2f(short h) {
    return __uint_as_float(((unsigned)(unsigned short)h) << 16);
}

// ---------------- fp32 VALU GEMM (down-proj only): C = A * B^T ----------------
template<bool BT>
__global__ __launch_bounds__(256)
void gemm_f32(const float* __restrict__ A, int lda, long sA,
              const float* __restrict__ B, int ldb, long sB,
              float* __restrict__ C, int ldc, long sC,
              int M, int N, int Kd, float alpha)
{
    long bz = blockIdx.z;
    A += bz * sA; B += bz * sB; C += bz * sC;
    int m0 = blockIdx.y * TILE, n0 = blockIdx.x * TILE;
    __shared__ float As[TK][TILE + 4];
    __shared__ float Bs[TK][TILE + 4];
    int tid = threadIdx.x;
    int tm = (tid >> 4) * 4;
    int tn = (tid & 15) * 4;
    float acc[4][4] = {};
    for (int k0 = 0; k0 < Kd; k0 += TK) {
        {
            int kk = tid & 15;
            int m  = tid >> 4;
            #pragma unroll
            for (int mm = 0; mm < 4; ++mm)
                As[kk][m + mm * 16] = A[(long)(m0 + m + mm * 16) * lda + k0 + kk];
        }
        {
            int kk = tid & 15;
            int n  = tid >> 4;
            #pragma unroll
            for (int nn = 0; nn < 4; ++nn)
                Bs[kk][n + nn * 16] = B[(long)(n0 + n + nn * 16) * ldb + k0 + kk];
        }
        __syncthreads();
        #pragma unroll
        for (int kk = 0; kk < TK; ++kk) {
            float4 a4 = *reinterpret_cast<const float4*>(&As[kk][tm]);
            float4 b4 = *reinterpret_cast<const float4*>(&Bs[kk][tn]);
            float a[4] = {a4.x, a4.y, a4.z, a4.w};
            float b[4] = {b4.x, b4.y, b4.z, b4.w};
            #pragma unroll
            for (int i = 0; i < 4; ++i)
                #pragma unroll
                for (int j = 0; j < 4; ++j)
                    acc[i][j] += a[i] * b[j];
        }
        __syncthreads();
    }
    #pragma unroll
    for (int i = 0; i < 4; ++i)
        #pragma unroll
        for (int j = 0; j < 4; ++j)
            C[(long)(m0 + tm + i) * ldc + n0 + tn + j] = alpha * acc[i][j];
}

// ---------------- m97-style bf16 MFMA GEMM: C (+)= alpha * A * B^T ----------------
// CMODE 0: C fp32 =, 1: C fp32 +=, 2: C^T bf16 (CT[n][m]), 3: C bf16 =
__device__ inline void gld_lds16(const __hip_bfloat16* g, __hip_bfloat16* l)
{
    __builtin_amdgcn_global_load_lds(
        (const __attribute__((address_space(1))) unsigned int*)g,
        (__attribute__((address_space(3))) unsigned int*)l,
        16, 0, 0);
}

template<int CMODE>
__global__ __launch_bounds__(256)
void gemm16(const __hip_bfloat16* __restrict__ A, int lda, long sA,
            const __hip_bfloat16* __restrict__ B, int ldb, long sB,
            void* __restrict__ Cv, int ldc, long sC,
            int Kd, float alpha)
{
    __shared__ __hip_bfloat16 As[128][32];
    __shared__ __hip_bfloat16 Bs[128][32];
    long bz = blockIdx.z;
    A += bz * sA; B += bz * sB;
    int m0 = blockIdx.y * 128, n0 = blockIdx.x * 128;
    int tid  = threadIdx.x;
    int w    = tid >> 6, lane = tid & 63;
    int wm   = w >> 1,  wn   = w & 1;
    int lrow = lane >> 2;
    int lseg = (lane & 3) * 8;
    int fr   = lane & 15;
    int kg   = (lane >> 4) * 8;
    f32x4 acc[4][4] = {};
    for (int k0 = 0; k0 < Kd; k0 += 32) {
        #pragma unroll
        for (int i = 0; i < 2; ++i) {
            int r = w * 32 + i * 16;
            gld_lds16(&A[(long)(m0 + r + lrow) * lda + k0 + lseg], &As[r][0]);
            gld_lds16(&B[(long)(n0 + r + lrow) * ldb + k0 + lseg], &Bs[r][0]);
        }
        __syncthreads();
        bf16x8 af[4], bfr[4];
        #pragma unroll
        for (int m = 0; m < 4; ++m)
            af[m] = *(const bf16x8*)&As[wm * 64 + m * 16 + fr][kg];
        #pragma unroll
        for (int n = 0; n < 4; ++n)
            bfr[n] = *(const bf16x8*)&Bs[wn * 64 + n * 16 + fr][kg];
        #pragma unroll
        for (int m = 0; m < 4; ++m)
            #pragma unroll
            for (int n = 0; n < 4; ++n)
                acc[m][n] = __builtin_amdgcn_mfma_f32_16x16x32_bf16(af[m], bfr[n], acc[m][n], 0, 0, 0);
        __syncthreads();
    }
    int crow0 = (lane >> 4) * 4;
    if constexpr (CMODE == 2) {
        __hip_bfloat16* CT = (__hip_bfloat16*)Cv + bz * sC;
        #pragma unroll
        for (int m = 0; m < 4; ++m)
            #pragma unroll
            for (int n = 0; n < 4; ++n)
                #pragma unroll
                for (int r = 0; r < 4; ++r) {
                    int row = m0 + wm * 64 + m * 16 + crow0 + r;
                    int col = n0 + wn * 64 + n * 16 + fr;
                    CT[(long)col * ldc + row] = __float2bfloat16(alpha * acc[m][n][r]);
                }
    } else if constexpr (CMODE == 3) {
        __hip_bfloat16* C = (__hip_bfloat16*)Cv + bz * sC;
        #pragma unroll
        for (int m = 0; m < 4; ++m)
            #pragma unroll
            for (int n = 0; n < 4; ++n)
                #pragma unroll
                for (int r = 0; r < 4; ++r)
                    C[(long)(m0 + wm * 64 + m * 16 + crow0 + r) * ldc
                      + n0 + wn * 64 + n * 16 + fr] = __float2bfloat16(alpha * acc[m][n][r]);
    } else {
        float* C = (float*)Cv + bz * sC;
        #pragma unroll
        for (int m = 0; m < 4; ++m)
            #pragma unroll
            for (int n = 0; n < 4; ++n)
                #pragma unroll
                for (int r = 0; r < 4; ++r) {
                    long idx = (long)(m0 + wm * 64 + m * 16 + crow0 + r) * ldc
                             + n0 + wn * 64 + n * 16 + fr;
                    float v = alpha * acc[m][n][r];
                    if constexpr (CMODE == 1) v += C[idx];
                    C[idx] = v;
                }
    }
}

// ---------------- merged Q+K 3-term split projection (atomic epilogue) ----------------
// blockIdx.x: [0,32) -> Q tile n0, [32,64) -> K tile n0-4096/128.
// z = term: 0 (AH,BH), 1 (AL,BH), 2 (AH,BL). Full K per block.
__global__ __launch_bounds__(256)
void gemm16_qk(const __hip_bfloat16* __restrict__ AH, const __hip_bfloat16* __restrict__ AL, int lda,
               const __hip_bfloat16* __restrict__ BqH, const __hip_bfloat16* __restrict__ BqL,
               const __hip_bfloat16* __restrict__ BkH, const __hip_bfloat16* __restrict__ BkL, int ldb,
               float* __restrict__ Cq, float* __restrict__ Ck, int ldc, int kSteps)
{
    __shared__ __hip_bfloat16 As[128][32];
    __shared__ __hip_bfloat16 Bs[128][32];
    int xsel = blockIdx.x >> 5;
    int n0   = (blockIdx.x & 31) * 128;
    int term = blockIdx.z;
    const __hip_bfloat16* A  = (term == 1) ? AL : AH;
    const __hip_bfloat16* BH = xsel ? BkH : BqH;
    const __hip_bfloat16* BL = xsel ? BkL : BqL;
    const __hip_bfloat16* B  = (term == 2) ? BL : BH;
    float* C = xsel ? Ck : Cq;
    int m0 = blockIdx.y * 128;
    int tid  = threadIdx.x;
    int w    = tid >> 6, lane = tid & 63;
    int wm   = w >> 1,  wn   = w & 1;
    int lrow = lane >> 2;
    int lseg = (lane & 3) * 8;
    int fr   = lane & 15;
    int kg   = (lane >> 4) * 8;
    f32x4 acc[4][4] = {};
    for (int it = 0; it < kSteps; ++it) {
        int k0 = it * 32;
        #pragma unroll
        for (int i = 0; i < 2; ++i) {
            int r = w * 32 + i * 16;
            gld_lds16(&A[(long)(m0 + r + lrow) * lda + k0 + lseg], &As[r][0]);
            gld_lds16(&B[(long)(n0 + r + lrow) * ldb + k0 + lseg], &Bs[r][0]);
        }
        __syncthreads();
        bf16x8 af[4], bfr[4];
        #pragma unroll
        for (int m = 0; m < 4; ++m)
            af[m] = *(const bf16x8*)&As[wm * 64 + m * 16 + fr][kg];
        #pragma unroll
        for (int n = 0; n < 4; ++n)
            bfr[n] = *(const bf16x8*)&Bs[wn * 64 + n * 16 + fr][kg];
        #pragma unroll
        for (int m = 0; m < 4; ++m)
            #pragma unroll
            for (int n = 0; n < 4; ++n)
                acc[m][n] = __builtin_amdgcn_mfma_f32_16x16x32_bf16(af[m], bfr[n], acc[m][n], 0, 0, 0);
        __syncthreads();
    }
    int crow0 = (lane >> 4) * 4;
    #pragma unroll
    for (int m = 0; m < 4; ++m)
        #pragma unroll
        for (int n = 0; n < 4; ++n)
            #pragma unroll
            for (int r = 0; r < 4; ++r) {
                long idx = (long)(m0 + wm * 64 + m * 16 + crow0 + r) * ldc
                         + n0 + wn * 64 + n * 16 + fr;
                atomicAdd(&C[idx], acc[m][n][r]);
            }
}

// ---------------- split-K/term bf16 MFMA GEMM with atomic accumulate (out proj) ----------------
__global__ __launch_bounds__(256)
void gemm16_sk(const __hip_bfloat16* __restrict__ A0, const __hip_bfloat16* __restrict__ A1,
               const __hip_bfloat16* __restrict__ A2, int lda,
               const __hip_bfloat16* __restrict__ B0, const __hip_bfloat16* __restrict__ B1,
               const __hip_bfloat16* __restrict__ B2, int ldb,
               float* __restrict__ C, int ldc,
               int kSteps, int chunksPerTerm, float alpha)
{
    __shared__ __hip_bfloat16 As[128][32];
    __shared__ __hip_bfloat16 Bs[128][32];
    int z    = blockIdx.z;
    int term = z / chunksPerTerm;
    int sub  = z - term * chunksPerTerm;
    const __hip_bfloat16* A = (term == 0) ? A0 : (term == 1) ? A1 : A2;
    const __hip_bfloat16* B = (term == 0) ? B0 : (term == 1) ? B1 : B2;
    int kbase = sub * kSteps * 32;
    int m0 = blockIdx.y * 128, n0 = blockIdx.x * 128;
    int tid  = threadIdx.x;
    int w    = tid >> 6, lane = tid & 63;
    int wm   = w >> 1,  wn   = w & 1;
    int lrow = lane >> 2;
    int lseg = (lane & 3) * 8;
    int fr   = lane & 15;
    int kg   = (lane >> 4) * 8;
    f32x4 acc[4][4] = {};
    for (int it = 0; it < kSteps; ++it) {
        int k0 = kbase + it * 32;
        #pragma unroll
        for (int i = 0; i < 2; ++i) {
            int r = w * 32 + i * 16;
            gld_lds16(&A[(long)(m0 + r + lrow) * lda + k0 + lseg], &As[r][0]);
            gld_lds16(&B[(long)(n0 + r + lrow) * ldb + k0 + lseg], &Bs[r][0]);
        }
        __syncthreads();
        bf16x8 af[4], bfr[4];
        #pragma unroll
        for (int m = 0; m < 4; ++m)
            af[m] = *(const bf16x8*)&As[wm * 64 + m * 16 + fr][kg];
        #pragma unroll
        for (int n = 0; n < 4; ++n)
            bfr[n] = *(const bf16x8*)&Bs[wn * 64 + n * 16 + fr][kg];
        #pragma unroll
        for (int m = 0; m < 4; ++m)
            #pragma unroll
            for (int n = 0; n < 4; ++n)
                acc[m][n] = __builtin_amdgcn_mfma_f32_16x16x32_bf16(af[m], bfr[n], acc[m][n], 0, 0, 0);
        __syncthreads();
    }
    int crow0 = (lane >> 4) * 4;
    #pragma unroll
    for (int m = 0; m < 4; ++m)
        #pragma unroll
        for (int n = 0; n < 4; ++n)
            #pragma unroll
            for (int r = 0; r < 4; ++r) {
                long idx = (long)(m0 + wm * 64 + m * 16 + crow0 + r) * ldc
                         + n0 + wn * 64 + n * 16 + fr;
                atomicAdd(&C[idx], alpha * acc[m][n][r]);
            }
}

// ---------------- in-register split MFMA GEMM (QK^T): C = alpha * A * B^T ----------------
#define LP 40
__global__ __launch_bounds__(256)
void gemm_s(const float* __restrict__ A, int lda, long sA,
            const float* __restrict__ B, int ldb, long sB,
            float* __restrict__ C, int ldc, long sC,
            int Kd, float alpha)
{
    __shared__ short Ah[128][LP];
    __shared__ short Bh[128][LP];
    __shared__ short Al[128][LP];
    __shared__ short Bl[128][LP];
    long bz = blockIdx.z;
    A += bz * sA; B += bz * sB; C += bz * sC;
    int m0 = blockIdx.y * 128, n0 = blockIdx.x * 128;
    int tid  = threadIdx.x;
    int lane = tid & 63;
    int w    = tid >> 6;
    int wm   = w >> 1, wn = w & 1;
    int srow = tid >> 1;
    int scol = (tid & 1) * 16;
    int fr   = lane & 15;
    int kg   = (lane >> 4) * 8;
    f32x4 acc[4][4] = {};
    for (int k0 = 0; k0 < Kd; k0 += 32) {
        #pragma unroll
        for (int ab = 0; ab < 2; ++ab) {
            const float* src = ab ? (B + (long)(n0 + srow) * ldb + k0 + scol)
                                  : (A + (long)(m0 + srow) * lda + k0 + scol);
            short* dh = ab ? &Bh[srow][scol] : &Ah[srow][scol];
            short* dl = ab ? &Bl[srow][scol] : &Al[srow][scol];
            #pragma unroll
            for (int half = 0; half < 2; ++half) {
                float4 x0 = *reinterpret_cast<const float4*>(src + half * 8);
                float4 x1 = *reinterpret_cast<const float4*>(src + half * 8 + 4);
                float xs[8] = {x0.x, x0.y, x0.z, x0.w, x1.x, x1.y, x1.z, x1.w};
                bf16x8 hv, lv;
                #pragma unroll
                for (int j = 0; j < 8; ++j) {
                    short hb = f2bf(xs[j]);
                    hv[j] = hb;
                    lv[j] = f2bf(xs[j] - bf2f(hb));
                }
                *reinterpret_cast<bf16x8*>(dh + half * 8) = hv;
                *reinterpret_cast<bf16x8*>(dl + half * 8) = lv;
            }
        }
        __syncthreads();
        bf16x8 afh[4], bfh[4], afl[4], bfl[4];
        #pragma unroll
        for (int m = 0; m < 4; ++m) {
            afh[m] = *(const bf16x8*)&Ah[wm * 64 + m * 16 + fr][kg];
            afl[m] = *(const bf16x8*)&Al[wm * 64 + m * 16 + fr][kg];
        }
        #pragma unroll
        for (int n = 0; n < 4; ++n) {
            bfh[n] = *(const bf16x8*)&Bh[wn * 64 + n * 16 + fr][kg];
            bfl[n] = *(const bf16x8*)&Bl[wn * 64 + n * 16 + fr][kg];
        }
        #pragma unroll
        for (int m = 0; m < 4; ++m)
            #pragma unroll
            for (int n = 0; n < 4; ++n) {
                acc[m][n] = __builtin_amdgcn_mfma_f32_16x16x32_bf16(afh[m], bfh[n], acc[m][n], 0, 0, 0);
                acc[m][n] = __builtin_amdgcn_mfma_f32_16x16x32_bf16(afh[m], bfl[n], acc[m][n], 0, 0, 0);
                acc[m][n] = __builtin_amdgcn_mfma_f32_16x16x32_bf16(afl[m], bfh[n], acc[m][n], 0, 0, 0);
            }
        __syncthreads();
    }
    int crow0 = (lane >> 4) * 4;
    #pragma unroll
    for (int m = 0; m < 4; ++m)
        #pragma unroll
        for (int n = 0; n < 4; ++n)
            #pragma unroll
            for (int r = 0; r < 4; ++r)
                C[(long)(m0 + wm * 64 + m * 16 + crow0 + r) * ldc
                  + n0 + wn * 64 + n * 16 + fr] = alpha * acc[m][n][r];
}

// ---------------- f32 -> bf16 hi or lo part (n4 = n/4) ----------------
struct alignas(8) s4 { short a, b, c, d; };
template<bool LO>
__global__ __launch_bounds__(256)
void cvt_part(const float* __restrict__ x, short* __restrict__ y, long n4)
{
    long i = (long)blockIdx.x * 256 + threadIdx.x;
    long stride = (long)gridDim.x * 256;
    for (; i < n4; i += stride) {
        float4 v = reinterpret_cast<const float4*>(x)[i];
        float xs[4] = {v.x, v.y, v.z, v.w};
        s4 o;
        short* op = &o.a;
        #pragma unroll
        for (int j = 0; j < 4; ++j) {
            short hb = f2bf(xs[j]);
            op[j] = LO ? f2bf(xs[j] - bf2f(hb)) : hb;
        }
        reinterpret_cast<s4*>(y)[i] = o;
    }
}

// ---------------- f32 -> bf16 hi AND lo in one pass ----------------
__global__ __launch_bounds__(256)
void cvt_both(const float* __restrict__ x, short* __restrict__ yh,
              short* __restrict__ yl, long n4)
{
    long i = (long)blockIdx.x * 256 + threadIdx.x;
    long stride = (long)gridDim.x * 256;
    for (; i < n4; i += stride) {
        float4 v = reinterpret_cast<const float4*>(x)[i];
        float xs[4] = {v.x, v.y, v.z, v.w};
        s4 oh, ol;
        short* hp = &oh.a; short* lp = &ol.a;
        #pragma unroll
        for (int j = 0; j < 4; ++j) {
            short hb = f2bf(xs[j]);
            hp[j] = hb;
            lp[j] = f2bf(xs[j] - bf2f(hb));
        }
        reinterpret_cast<s4*>(yh)[i] = oh;
        reinterpret_cast<s4*>(yl)[i] = ol;
    }
}

// ---------------- RoPE in place on q,k [S][4096] ----------------
__global__ __launch_bounds__(256)
void rope_kernel(float* __restrict__ q, float* __restrict__ k, const int* __restrict__ pos)
{
    int i = blockIdx.x * 256 + threadIdx.x;
    if (i >= 1024 * 32 * 64) return;
    int d   = i & 63;
    int rem = i >> 6;
    int h   = rem & 31;
    int s   = rem >> 5;
    float p = (float)pos[s];
    float inv = exp2f(-(float)d * (13.287712379549449f / 64.0f));
    float ang = p * inv;
    float c = cosf(ang), sn = sinf(ang);
    long base = ((long)s * 4096) + h * 128 + d;
    float x1 = q[base], x2 = q[base + 64];
    q[base]      = x1 * c - x2 * sn;
    q[base + 64] = x2 * c + x1 * sn;
    x1 = k[base]; x2 = k[base + 64];
    k[base]      = x1 * c - x2 * sn;
    k[base + 64] = x2 * c + x1 * sn;
}

// ---------------- row stats: est + LN1 scale/offset from raw scores (one read) ----------------
__global__ __launch_bounds__(256)
void row_stats(const float* __restrict__ x,
               const float* __restrict__ sw, const float* __restrict__ sbias,
               float* __restrict__ est, float* __restrict__ lnA, float* __restrict__ lnO)
{
    long row = blockIdx.x;
    const float* xr = x + row * 1024;
    __shared__ float sb[12];
    float s = 0.f, ss = 0.f, dt = 0.f;
    #pragma unroll
    for (int i = 0; i < 4; ++i) {
        int c = threadIdx.x + i * 256;
        float v = xr[c];
        s += v; ss += v * v; dt += v * sw[c];
    }
    #pragma unroll
    for (int off = 32; off; off >>= 1) {
        s  += __shfl_down(s, off, 64);
        ss += __shfl_down(ss, off, 64);
        dt += __shfl_down(dt, off, 64);
    }
    int wid = threadIdx.x >> 6, lane = threadIdx.x & 63;
    if (!lane) { sb[wid] = s; sb[4 + wid] = ss; sb[8 + wid] = dt; }
    __syncthreads();
    if (threadIdx.x == 0) {
        s  = sb[0] + sb[1] + sb[2] + sb[3];
        ss = sb[4] + sb[5] + sb[6] + sb[7];
        float mean = s * (1.f / 1024.f);
        float var  = ss * (1.f / 1024.f) - mean * mean;
        float a    = rsqrtf(var + 1e-5f);
        est[row] = sb[8] + sb[9] + sb[10] + sb[11] + sbias[0];
        lnA[row] = a;
        lnO[row] = -mean * a;
    }
}

// ---------------- conv layer 0 with LN1 fused; lnA/lnO staged in LDS ----------------
__global__ __launch_bounds__(256)
void conv_ln1(const float* __restrict__ x, float* __restrict__ y,
              const float* __restrict__ cw, const float* __restrict__ cb,
              const float* __restrict__ lnA, const float* __restrict__ lnO,
              const float* __restrict__ w1, const float* __restrict__ b1, int h0)
{
    const int S = 1024;
    int h  = blockIdx.z;
    int hg = h0 + h;
    int q0 = blockIdx.y * 64;
    int k0 = blockIdx.x * 64;
    __shared__ float ws[63];
    __shared__ float sA[126];
    __shared__ float sO[126];
    int tid = threadIdx.x;
    if (tid < 63) ws[tid] = cw[hg * 63 + tid];
    if (tid < 126) {
        int g = q0 - 62 + tid;
        const float* lA = lnA + (long)h * S;
        const float* lO = lnO + (long)h * S;
        sA[tid] = (g >= 0) ? lA[g] : 0.f;
        sO[tid] = (g >= 0) ? lO[g] : 0.f;
    }
    __syncthreads();
    int c   = tid & 63;
    int grp = tid >> 6;
    int qb  = q0 + grp * 16;
    float wc = w1[k0 + c];
    float bc = b1[k0 + c];
    const float* xh = x + (long)h * S * S + k0 + c;
    float X[78];
    #pragma unroll
    for (int j = 0; j < 78; ++j) {
        int g = qb - 62 + j;
        int rl = grp * 16 + j;            // LDS row index, 0..125
        if (g >= 0) {
            float raw = xh[(long)g * S];
            X[j] = fmaf(raw * sA[rl] + sO[rl], wc, bc);
        } else X[j] = 0.f;
    }
    float wr[63];
    #pragma unroll
    for (int t = 0; t < 63; ++t) wr[t] = ws[t];
    float bias = cb[hg];
    float* yh = y + (long)h * S * S + k0 + c;
    #pragma unroll
    for (int i = 0; i < 16; ++i) {
        float a0 = 0.f, a1 = 0.f, a2 = 0.f, a3 = 0.f;
        #pragma unroll
        for (int t = 0; t < 60; t += 4) {
            a0 += wr[t]     * X[i + t];
            a1 += wr[t + 1] * X[i + t + 1];
            a2 += wr[t + 2] * X[i + t + 2];
            a3 += wr[t + 3] * X[i + t + 3];
        }
        a0 += wr[60] * X[i + 60];
        a1 += wr[61] * X[i + 61];
        a2 += wr[62] * X[i + 62];
        float acc = bias + ((a0 + a1) + (a2 + a3));
        yh[(long)(qb + i) * S] = fmaxf(acc, 0.f);
    }
}

// ---------------- causal depthwise conv + ReLU, register-tap (layers 1,2) ----------------
__global__ __launch_bounds__(256)
void conv_fast(const float* __restrict__ x, float* __restrict__ y,
               const float* __restrict__ cw, const float* __restrict__ cb,
               int layer, int h0)
{
    const int S = 1024;
    int h  = blockIdx.z;
    int hg = h0 + h;
    int q0 = blockIdx.y * 64;
    int k0 = blockIdx.x * 64;
    __shared__ float ws[63];
    if (threadIdx.x < 63) ws[threadIdx.x] = cw[(layer * 32 + hg) * 63 + threadIdx.x];
    __syncthreads();
    int c   = threadIdx.x & 63;
    int grp = threadIdx.x >> 6;
    int qb  = q0 + grp * 16;
    const float* xh = x + (long)h * S * S + k0 + c;
    float X[78];
    #pragma unroll
    for (int j = 0; j < 78; ++j) {
        int g = qb - 62 + j;
        X[j] = (g >= 0) ? xh[(long)g * S] : 0.f;
    }
    float wr[63];
    #pragma unroll
    for (int t = 0; t < 63; ++t) wr[t] = ws[t];
    float bias = cb[layer * 32 + hg];
    float* yh = y + (long)h * S * S + k0 + c;
    #pragma unroll
    for (int i = 0; i < 16; ++i) {
        float a0 = 0.f, a1 = 0.f, a2 = 0.f, a3 = 0.f;
        #pragma unroll
        for (int t = 0; t < 60; t += 4) {
            a0 += wr[t]     * X[i + t];
            a1 += wr[t + 1] * X[i + t + 1];
            a2 += wr[t + 2] * X[i + t + 2];
            a3 += wr[t + 3] * X[i + t + 3];
        }
        a0 += wr[60] * X[i + 60];
        a1 += wr[61] * X[i + 61];
        a2 += wr[62] * X[i + 62];
        float acc = bias + ((a0 + a1) + (a2 + a3));
        yh[(long)(qb + i) * S] = fmaxf(acc, 0.f);
    }
}

// ---------------- fused LayerNorm2 + mask + softmax + sigmoid gate -> bf16 p ----------------
__global__ __launch_bounds__(256)
void ln2_softmax(const float* __restrict__ x, __hip_bfloat16* __restrict__ pb,
                 const float* __restrict__ w, const float* __restrict__ b,
                 const float* __restrict__ mask, const float* __restrict__ est)
{
    const int S = 1024;
    long row = blockIdx.x;
    int q = (int)(row & (S - 1));
    const float* xr = x + row * 1024;
    const float* mrow = mask + (long)q * S;
    __shared__ float sb[8];
    float v[4];
    float s = 0.f, ss = 0.f;
    #pragma unroll
    for (int i = 0; i < 4; ++i) {
        int c = threadIdx.x + i * 256;
        v[i] = xr[c];
        s += v[i]; ss += v[i] * v[i];
    }
    #pragma unroll
    for (int off = 32; off; off >>= 1) {
        s  += __shfl_down(s, off, 64);
        ss += __shfl_down(ss, off, 64);
    }
    int wid = threadIdx.x >> 6, lane = threadIdx.x & 63;
    if (!lane) { sb[wid] = s; sb[4 + wid] = ss; }
    __syncthreads();
    s  = sb[0] + sb[1] + sb[2] + sb[3];
    ss = sb[4] + sb[5] + sb[6] + sb[7];
    float mean = s * (1.f / 1024.f);
    float var  = ss * (1.f / 1024.f) - mean * mean;
    float inv  = rsqrtf(var + 1e-5f);
    const float FMIN = -3.4028235e38f;
    float mx = FMIN;
    #pragma unroll
    for (int i = 0; i < 4; ++i) {
        int c = threadIdx.x + i * 256;
        float t = (v[i] - mean) * inv * w[c] + b[c] + mrow[c];
        t = fmaxf(t, FMIN);
        v[i] = t;
        mx = fmaxf(mx, t);
    }
    #pragma unroll
    for (int off = 32; off; off >>= 1) mx = fmaxf(mx, __shfl_down(mx, off, 64));
    __syncthreads();
    if (!lane) sb[wid] = mx;
    __syncthreads();
    mx = fmaxf(fmaxf(sb[0], sb[1]), fmaxf(sb[2], sb[3]));
    float s2 = 0.f;
    #pragma unroll
    for (int i = 0; i < 4; ++i) { v[i] = expf(v[i] - mx); s2 += v[i]; }
    #pragma unroll
    for (int off = 32; off; off >>= 1) s2 += __shfl_down(s2, off, 64);
    __syncthreads();
    if (!lane) sb[4 + wid] = s2;
    __syncthreads();
    s2 = sb[4] + sb[5] + sb[6] + sb[7];
    float e = est[row];
    float sc = (1.f / (1.f + expf(-e))) / s2;
    __hip_bfloat16* pr = pb + row * S;
    #pragma unroll
    for (int i = 0; i < 4; ++i) {
        int c = threadIdx.x + i * 256;
        pr[c] = __float2bfloat16(v[i] * sc);
    }
}

extern "C" void kernel_launch(void* const* d_in, const int* in_sizes, int n_in,
                              void* d_out, int out_size, void* d_ws, size_t ws_size,
                              hipStream_t stream) {
    const int S = 1024, H = 32, HID = 4096, DH = 128, DL = 64;

    const float* hs   = (const float*)d_in[0];
    const float* mask = (const float*)d_in[1];
    const int*   pos  = (const int*)d_in[2];
    const float* Wq   = (const float*)d_in[3];
    const float* Wk   = (const float*)d_in[4];
    const float* Wv   = (const float*)d_in[5];
    const float* Wo   = (const float*)d_in[6];
    const float* Wdq  = (const float*)d_in[7];
    const float* Wdk  = (const float*)d_in[8];
    const float* ln1w = (const float*)d_in[9];
    const float* ln1b = (const float*)d_in[10];
    const float* ln2w = (const float*)d_in[11];
    const float* ln2b = (const float*)d_in[12];
    const float* cw   = (const float*)d_in[13];
    const float* cb   = (const float*)d_in[14];
    const float* sw   = (const float*)d_in[15];
    const float* sbia = (const float*)d_in[16];
    float* out = (float*)d_out;

    // ---- workspace layout (floats) ----
    float* p   = (float*)d_ws;
    float* qb  = p; p += (long)S * HID;
    float* kb  = p; p += (long)S * HID;
    float* ql  = p; p += (long)H * S * DL;
    float* kl  = p; p += (long)H * S * DL;
    float* est = p; p += (long)H * S;
    float* lnA = p; p += (long)H * S;
    float* lnO = p; p += (long)H * S;
    short* hsH = (short*)p; p += (long)S * HID / 2;   // later aoH
    short* hsL = (short*)p; p += (long)S * HID / 2;   // later vT bf16
    short* WbH  = (short*)p; p += (long)HID * HID / 2; // Wq hi (later Wv/Wo hi)
    short* WbL  = (short*)p; p += (long)HID * HID / 2; // Wq lo
    short* Wk2H = (short*)p; p += (long)HID * HID / 2; // Wk hi
    short* Wk2L = (short*)p; p += (long)HID * HID / 2; // Wk lo
    short* aoH = hsH;
    short* vT  = hsL;   // [H][128][1024] bf16

    long wsFloats  = (long)(ws_size / 4);
    long usedFixed = p - (float*)d_ws;
    long perHead   = 2L * S * S;
    int CH = (int)((wsFloats - usedFixed) / perHead);
    if (CH > H) CH = H;
    if (CH < 1) CH = 1;
    float* sc0 = p;
    float* sc1 = sc0 + (long)CH * S * S;
    __hip_bfloat16* pb = (__hip_bfloat16*)sc0;   // alias: sc0 dead after conv3

    dim3 blk(256);
    long n4_hs = (long)S * HID / 4, n4_W = (long)HID * HID / 4;
    size_t projBytes = (size_t)S * HID * sizeof(float);

    // hs -> hi/lo bf16
    cvt_both<<<2048, blk, 0, stream>>>(hs, hsH, hsL, n4_hs);

    // ---- merged Q+K projection: one launch, 3 terms, full K ----
    hipMemsetAsync(qb, 0, projBytes, stream);
    hipMemsetAsync(kb, 0, projBytes, stream);
    cvt_both<<<2048, blk, 0, stream>>>(Wq, WbH, WbL, n4_W);
    cvt_both<<<2048, blk, 0, stream>>>(Wk, Wk2H, Wk2L, n4_W);
    gemm16_qk<<<dim3(64, S / 128, 3), blk, 0, stream>>>(
        (__hip_bfloat16*)hsH, (__hip_bfloat16*)hsL, HID,
        (__hip_bfloat16*)WbH, (__hip_bfloat16*)WbL,
        (__hip_bfloat16*)Wk2H, (__hip_bfloat16*)Wk2L, HID,
        qb, kb, HID, HID / 32);

    // ---- V projection: hi-only, write vT bf16 [H][128][1024] directly ----
    cvt_part<false><<<2048, blk, 0, stream>>>(Wv, WbH, n4_W);
    gemm16<2><<<dim3(HID / 128, S / 128, 1), blk, 0, stream>>>(
        (__hip_bfloat16*)hsH, HID, 0, (__hip_bfloat16*)WbH, HID, 0, vT, S, 0, HID, 1.f);

    rope_kernel<<<(S * H * 64 + 255) / 256, blk, 0, stream>>>(qb, kb, pos);

    // low-rank down-proj (fp32 VALU, exact)
    gemm_f32<true><<<dim3(1, S / 64, H), blk, 0, stream>>>(qb, HID, 128, Wdq, DH, 0, ql, DL, (long)S * DL, S, DL, DH, 1.f);
    gemm_f32<true><<<dim3(1, S / 64, H), blk, 0, stream>>>(kb, HID, 128, Wdk, DH, 0, kl, DL, (long)S * DL, S, DL, DH, 1.f);

    for (int c0 = 0; c0 < H; c0 += CH) {
        int ch = (c0 + CH <= H) ? CH : (H - c0);
        gemm_s<<<dim3(S / 128, S / 128, ch), blk, 0, stream>>>(
            ql + (long)c0 * S * DL, DL, (long)S * DL,
            kl + (long)c0 * S * DL, DL, (long)S * DL,
            sc0, S, (long)S * S, DL, 0.125f);
        row_stats<<<ch * S, blk, 0, stream>>>(sc0, sw, sbia,
            est + (long)c0 * S, lnA + (long)c0 * S, lnO + (long)c0 * S);
        conv_ln1<<<dim3(16, 16, ch), blk, 0, stream>>>(sc0, sc1, cw, cb,
            lnA + (long)c0 * S, lnO + (long)c0 * S, ln1w, ln1b, c0);
        conv_fast<<<dim3(16, 16, ch), blk, 0, stream>>>(sc1, sc0, cw, cb, 1, c0);
        conv_fast<<<dim3(16, 16, ch), blk, 0, stream>>>(sc0, sc1, cw, cb, 2, c0);
        ln2_softmax<<<ch * S, blk, 0, stream>>>(sc1, pb, ln2w, ln2b, mask, est + (long)c0 * S);
        gemm16<3><<<dim3(1, S / 128, ch), blk, 0, stream>>>(
            (__hip_bfloat16*)pb, S, (long)S * S,
            (__hip_bfloat16*)(vT + (long)c0 * DH * S), S, (long)DH * S,
            aoH + (long)c0 * 128, HID, 128,
            S, 1.f);
    }

    // ---- final: out = aoH @ Wo^T (hi-only bf16, split-K atomic, z=2) ----
    cvt_part<false><<<2048, blk, 0, stream>>>(Wo, WbH, n4_W);
    hipMemsetAsync(out, 0, projBytes, stream);
    gemm16_sk<<<dim3(HID / 128, S / 128, 2), blk, 0, stream>>>(
        (__hip_bfloat16*)aoH, (__hip_bfloat16*)aoH, (__hip_bfloat16*)aoH, HID,
        (__hip_bfloat16*)WbH, (__hip_bfloat16*)WbH, (__hip_bfloat16*)WbH, HID,
        out, HID, 64, 2, 1.f);
}

// Round 12
// 1324.193 us; speedup vs baseline: 1.0680x; 1.0680x over previous
//
#include <hip/hip_runtime.h>
#include <hip/hip_bf16.h>

typedef __attribute__((ext_vector_type(8))) short bf16x8;
typedef __attribute__((ext_vector_type(4))) float f32x4;

#define TILE 64
#define TK 16

__device__ inline short f2bf(float x) {
    unsigned u = __float_as_uint(x);
    unsigned r = (u + 0x7fffu + ((u >> 16) & 1u)) >> 16;
    return (short)r;
}
__device__ inline float bf2f(short h) {
    return __uint_as_float(((unsigned)(unsigned short)h) << 16);
}

// ---------------- fp32 VALU GEMM (down-proj only): C = A * B^T ----------------
template<bool BT>
__global__ __launch_bounds__(256)
void gemm_f32(const float* __restrict__ A, int lda, long sA,
              const float* __restrict__ B, int ldb, long sB,
              float* __restrict__ C, int ldc, long sC,
              int M, int N, int Kd, float alpha)
{
    long bz = blockIdx.z;
    A += bz * sA; B += bz * sB; C += bz * sC;
    int m0 = blockIdx.y * TILE, n0 = blockIdx.x * TILE;
    __shared__ float As[TK][TILE + 4];
    __shared__ float Bs[TK][TILE + 4];
    int tid = threadIdx.x;
    int tm = (tid >> 4) * 4;
    int tn = (tid & 15) * 4;
    float acc[4][4] = {};
    for (int k0 = 0; k0 < Kd; k0 += TK) {
        {
            int kk = tid & 15;
            int m  = tid >> 4;
            #pragma unroll
            for (int mm = 0; mm < 4; ++mm)
                As[kk][m + mm * 16] = A[(long)(m0 + m + mm * 16) * lda + k0 + kk];
        }
        {
            int kk = tid & 15;
            int n  = tid >> 4;
            #pragma unroll
            for (int nn = 0; nn < 4; ++nn)
                Bs[kk][n + nn * 16] = B[(long)(n0 + n + nn * 16) * ldb + k0 + kk];
        }
        __syncthreads();
        #pragma unroll
        for (int kk = 0; kk < TK; ++kk) {
            float4 a4 = *reinterpret_cast<const float4*>(&As[kk][tm]);
            float4 b4 = *reinterpret_cast<const float4*>(&Bs[kk][tn]);
            float a[4] = {a4.x, a4.y, a4.z, a4.w};
            float b[4] = {b4.x, b4.y, b4.z, b4.w};
            #pragma unroll
            for (int i = 0; i < 4; ++i)
                #pragma unroll
                for (int j = 0; j < 4; ++j)
                    acc[i][j] += a[i] * b[j];
        }
        __syncthreads();
    }
    #pragma unroll
    for (int i = 0; i < 4; ++i)
        #pragma unroll
        for (int j = 0; j < 4; ++j)
            C[(long)(m0 + tm + i) * ldc + n0 + tn + j] = alpha * acc[i][j];
}

// ---------------- m97-style bf16 MFMA GEMM: C (+)= alpha * A * B^T ----------------
// CMODE 0: C fp32 =, 1: C fp32 +=, 2: C^T bf16 (CT[n][m]), 3: C bf16 =
__device__ inline void gld_lds16(const __hip_bfloat16* g, __hip_bfloat16* l)
{
    __builtin_amdgcn_global_load_lds(
        (const __attribute__((address_space(1))) unsigned int*)g,
        (__attribute__((address_space(3))) unsigned int*)l,
        16, 0, 0);
}

template<int CMODE>
__global__ __launch_bounds__(256)
void gemm16(const __hip_bfloat16* __restrict__ A, int lda, long sA,
            const __hip_bfloat16* __restrict__ B, int ldb, long sB,
            void* __restrict__ Cv, int ldc, long sC,
            int Kd, float alpha)
{
    __shared__ __hip_bfloat16 As[128][32];
    __shared__ __hip_bfloat16 Bs[128][32];
    long bz = blockIdx.z;
    A += bz * sA; B += bz * sB;
    int m0 = blockIdx.y * 128, n0 = blockIdx.x * 128;
    int tid  = threadIdx.x;
    int w    = tid >> 6, lane = tid & 63;
    int wm   = w >> 1,  wn   = w & 1;
    int lrow = lane >> 2;
    int lseg = (lane & 3) * 8;
    int fr   = lane & 15;
    int kg   = (lane >> 4) * 8;
    f32x4 acc[4][4] = {};
    for (int k0 = 0; k0 < Kd; k0 += 32) {
        #pragma unroll
        for (int i = 0; i < 2; ++i) {
            int r = w * 32 + i * 16;
            gld_lds16(&A[(long)(m0 + r + lrow) * lda + k0 + lseg], &As[r][0]);
            gld_lds16(&B[(long)(n0 + r + lrow) * ldb + k0 + lseg], &Bs[r][0]);
        }
        __syncthreads();
        bf16x8 af[4], bfr[4];
        #pragma unroll
        for (int m = 0; m < 4; ++m)
            af[m] = *(const bf16x8*)&As[wm * 64 + m * 16 + fr][kg];
        #pragma unroll
        for (int n = 0; n < 4; ++n)
            bfr[n] = *(const bf16x8*)&Bs[wn * 64 + n * 16 + fr][kg];
        #pragma unroll
        for (int m = 0; m < 4; ++m)
            #pragma unroll
            for (int n = 0; n < 4; ++n)
                acc[m][n] = __builtin_amdgcn_mfma_f32_16x16x32_bf16(af[m], bfr[n], acc[m][n], 0, 0, 0);
        __syncthreads();
    }
    int crow0 = (lane >> 4) * 4;
    if constexpr (CMODE == 2) {
        __hip_bfloat16* CT = (__hip_bfloat16*)Cv + bz * sC;
        #pragma unroll
        for (int m = 0; m < 4; ++m)
            #pragma unroll
            for (int n = 0; n < 4; ++n)
                #pragma unroll
                for (int r = 0; r < 4; ++r) {
                    int row = m0 + wm * 64 + m * 16 + crow0 + r;
                    int col = n0 + wn * 64 + n * 16 + fr;
                    CT[(long)col * ldc + row] = __float2bfloat16(alpha * acc[m][n][r]);
                }
    } else if constexpr (CMODE == 3) {
        __hip_bfloat16* C = (__hip_bfloat16*)Cv + bz * sC;
        #pragma unroll
        for (int m = 0; m < 4; ++m)
            #pragma unroll
            for (int n = 0; n < 4; ++n)
                #pragma unroll
                for (int r = 0; r < 4; ++r)
                    C[(long)(m0 + wm * 64 + m * 16 + crow0 + r) * ldc
                      + n0 + wn * 64 + n * 16 + fr] = __float2bfloat16(alpha * acc[m][n][r]);
    } else {
        float* C = (float*)Cv + bz * sC;
        #pragma unroll
        for (int m = 0; m < 4; ++m)
            #pragma unroll
            for (int n = 0; n < 4; ++n)
                #pragma unroll
                for (int r = 0; r < 4; ++r) {
                    long idx = (long)(m0 + wm * 64 + m * 16 + crow0 + r) * ldc
                             + n0 + wn * 64 + n * 16 + fr;
                    float v = alpha * acc[m][n][r];
                    if constexpr (CMODE == 1) v += C[idx];
                    C[idx] = v;
                }
    }
}

// ---------------- split-K/term bf16 MFMA GEMM with atomic accumulate ----------------
__global__ __launch_bounds__(256)
void gemm16_sk(const __hip_bfloat16* __restrict__ A0, const __hip_bfloat16* __restrict__ A1,
               const __hip_bfloat16* __restrict__ A2, int lda,
               const __hip_bfloat16* __restrict__ B0, const __hip_bfloat16* __restrict__ B1,
               const __hip_bfloat16* __restrict__ B2, int ldb,
               float* __restrict__ C, int ldc,
               int kSteps, int chunksPerTerm, float alpha)
{
    __shared__ __hip_bfloat16 As[128][32];
    __shared__ __hip_bfloat16 Bs[128][32];
    int z    = blockIdx.z;
    int term = z / chunksPerTerm;
    int sub  = z - term * chunksPerTerm;
    const __hip_bfloat16* A = (term == 0) ? A0 : (term == 1) ? A1 : A2;
    const __hip_bfloat16* B = (term == 0) ? B0 : (term == 1) ? B1 : B2;
    int kbase = sub * kSteps * 32;
    int m0 = blockIdx.y * 128, n0 = blockIdx.x * 128;
    int tid  = threadIdx.x;
    int w    = tid >> 6, lane = tid & 63;
    int wm   = w >> 1,  wn   = w & 1;
    int lrow = lane >> 2;
    int lseg = (lane & 3) * 8;
    int fr   = lane & 15;
    int kg   = (lane >> 4) * 8;
    f32x4 acc[4][4] = {};
    for (int it = 0; it < kSteps; ++it) {
        int k0 = kbase + it * 32;
        #pragma unroll
        for (int i = 0; i < 2; ++i) {
            int r = w * 32 + i * 16;
            gld_lds16(&A[(long)(m0 + r + lrow) * lda + k0 + lseg], &As[r][0]);
            gld_lds16(&B[(long)(n0 + r + lrow) * ldb + k0 + lseg], &Bs[r][0]);
        }
        __syncthreads();
        bf16x8 af[4], bfr[4];
        #pragma unroll
        for (int m = 0; m < 4; ++m)
            af[m] = *(const bf16x8*)&As[wm * 64 + m * 16 + fr][kg];
        #pragma unroll
        for (int n = 0; n < 4; ++n)
            bfr[n] = *(const bf16x8*)&Bs[wn * 64 + n * 16 + fr][kg];
        #pragma unroll
        for (int m = 0; m < 4; ++m)
            #pragma unroll
            for (int n = 0; n < 4; ++n)
                acc[m][n] = __builtin_amdgcn_mfma_f32_16x16x32_bf16(af[m], bfr[n], acc[m][n], 0, 0, 0);
        __syncthreads();
    }
    int crow0 = (lane >> 4) * 4;
    #pragma unroll
    for (int m = 0; m < 4; ++m)
        #pragma unroll
        for (int n = 0; n < 4; ++n)
            #pragma unroll
            for (int r = 0; r < 4; ++r) {
                long idx = (long)(m0 + wm * 64 + m * 16 + crow0 + r) * ldc
                         + n0 + wn * 64 + n * 16 + fr;
                atomicAdd(&C[idx], alpha * acc[m][n][r]);
            }
}

// ---------------- PV GEMM, 64x128 tile: aoH bf16 = pb * vT^T ----------------
__global__ __launch_bounds__(256)
void gemm_pv(const __hip_bfloat16* __restrict__ Ab, long sA,
             const __hip_bfloat16* __restrict__ Bb, long sB,
             __hip_bfloat16* __restrict__ C, int ldc, long sC)
{
    __shared__ __hip_bfloat16 As[64][32];
    __shared__ __hip_bfloat16 Bs[128][32];
    const int S = 1024;
    int h  = blockIdx.y;
    const __hip_bfloat16* A = Ab + (long)h * sA;
    const __hip_bfloat16* B = Bb + (long)h * sB;
    __hip_bfloat16* Ch = C + (long)h * sC;
    int m0 = blockIdx.x * 64;
    int tid  = threadIdx.x;
    int w    = tid >> 6, lane = tid & 63;
    int wm   = w >> 1,  wn   = w & 1;
    int lrow = lane >> 2;
    int lseg = (lane & 3) * 8;
    int fr   = lane & 15;
    int kg   = (lane >> 4) * 8;
    f32x4 acc[2][4] = {};
    for (int k0 = 0; k0 < S; k0 += 32) {
        gld_lds16(&A[(long)(m0 + w * 16 + lrow) * S + k0 + lseg], &As[w * 16][0]);
        #pragma unroll
        for (int i = 0; i < 2; ++i) {
            int r = w * 32 + i * 16;
            gld_lds16(&B[(long)(r + lrow) * S + k0 + lseg], &Bs[r][0]);
        }
        __syncthreads();
        bf16x8 af[2], bfr[4];
        #pragma unroll
        for (int m = 0; m < 2; ++m)
            af[m] = *(const bf16x8*)&As[wm * 32 + m * 16 + fr][kg];
        #pragma unroll
        for (int n = 0; n < 4; ++n)
            bfr[n] = *(const bf16x8*)&Bs[wn * 64 + n * 16 + fr][kg];
        #pragma unroll
        for (int m = 0; m < 2; ++m)
            #pragma unroll
            for (int n = 0; n < 4; ++n)
                acc[m][n] = __builtin_amdgcn_mfma_f32_16x16x32_bf16(af[m], bfr[n], acc[m][n], 0, 0, 0);
        __syncthreads();
    }
    int crow0 = (lane >> 4) * 4;
    #pragma unroll
    for (int m = 0; m < 2; ++m)
        #pragma unroll
        for (int n = 0; n < 4; ++n)
            #pragma unroll
            for (int r = 0; r < 4; ++r)
                Ch[(long)(m0 + wm * 32 + m * 16 + crow0 + r) * ldc
                   + wn * 64 + n * 16 + fr] = __float2bfloat16(acc[m][n][r]);
}

// ---------------- in-register split MFMA GEMM (QK^T): C = alpha * A * B^T ----------------
#define LP 40
__global__ __launch_bounds__(256)
void gemm_s(const float* __restrict__ A, int lda, long sA,
            const float* __restrict__ B, int ldb, long sB,
            float* __restrict__ C, int ldc, long sC,
            int Kd, float alpha)
{
    __shared__ short Ah[128][LP];
    __shared__ short Bh[128][LP];
    __shared__ short Al[128][LP];
    __shared__ short Bl[128][LP];
    long bz = blockIdx.z;
    A += bz * sA; B += bz * sB; C += bz * sC;
    int m0 = blockIdx.y * 128, n0 = blockIdx.x * 128;
    int tid  = threadIdx.x;
    int lane = tid & 63;
    int w    = tid >> 6;
    int wm   = w >> 1, wn = w & 1;
    int srow = tid >> 1;
    int scol = (tid & 1) * 16;
    int fr   = lane & 15;
    int kg   = (lane >> 4) * 8;
    f32x4 acc[4][4] = {};
    for (int k0 = 0; k0 < Kd; k0 += 32) {
        #pragma unroll
        for (int ab = 0; ab < 2; ++ab) {
            const float* src = ab ? (B + (long)(n0 + srow) * ldb + k0 + scol)
                                  : (A + (long)(m0 + srow) * lda + k0 + scol);
            short* dh = ab ? &Bh[srow][scol] : &Ah[srow][scol];
            short* dl = ab ? &Bl[srow][scol] : &Al[srow][scol];
            #pragma unroll
            for (int half = 0; half < 2; ++half) {
                float4 x0 = *reinterpret_cast<const float4*>(src + half * 8);
                float4 x1 = *reinterpret_cast<const float4*>(src + half * 8 + 4);
                float xs[8] = {x0.x, x0.y, x0.z, x0.w, x1.x, x1.y, x1.z, x1.w};
                bf16x8 hv, lv;
                #pragma unroll
                for (int j = 0; j < 8; ++j) {
                    short hb = f2bf(xs[j]);
                    hv[j] = hb;
                    lv[j] = f2bf(xs[j] - bf2f(hb));
                }
                *reinterpret_cast<bf16x8*>(dh + half * 8) = hv;
                *reinterpret_cast<bf16x8*>(dl + half * 8) = lv;
            }
        }
        __syncthreads();
        bf16x8 afh[4], bfh[4], afl[4], bfl[4];
        #pragma unroll
        for (int m = 0; m < 4; ++m) {
            afh[m] = *(const bf16x8*)&Ah[wm * 64 + m * 16 + fr][kg];
            afl[m] = *(const bf16x8*)&Al[wm * 64 + m * 16 + fr][kg];
        }
        #pragma unroll
        for (int n = 0; n < 4; ++n) {
            bfh[n] = *(const bf16x8*)&Bh[wn * 64 + n * 16 + fr][kg];
            bfl[n] = *(const bf16x8*)&Bl[wn * 64 + n * 16 + fr][kg];
        }
        #pragma unroll
        for (int m = 0; m < 4; ++m)
            #pragma unroll
            for (int n = 0; n < 4; ++n) {
                acc[m][n] = __builtin_amdgcn_mfma_f32_16x16x32_bf16(afh[m], bfh[n], acc[m][n], 0, 0, 0);
                acc[m][n] = __builtin_amdgcn_mfma_f32_16x16x32_bf16(afh[m], bfl[n], acc[m][n], 0, 0, 0);
                acc[m][n] = __builtin_amdgcn_mfma_f32_16x16x32_bf16(afl[m], bfh[n], acc[m][n], 0, 0, 0);
            }
        __syncthreads();
    }
    int crow0 = (lane >> 4) * 4;
    #pragma unroll
    for (int m = 0; m < 4; ++m)
        #pragma unroll
        for (int n = 0; n < 4; ++n)
            #pragma unroll
            for (int r = 0; r < 4; ++r)
                C[(long)(m0 + wm * 64 + m * 16 + crow0 + r) * ldc
                  + n0 + wn * 64 + n * 16 + fr] = alpha * acc[m][n][r];
}

// ---------------- f32 -> bf16 hi or lo part (n4 = n/4) ----------------
struct alignas(8) s4 { short a, b, c, d; };
template<bool LO>
__global__ __launch_bounds__(256)
void cvt_part(const float* __restrict__ x, short* __restrict__ y, long n4)
{
    long i = (long)blockIdx.x * 256 + threadIdx.x;
    long stride = (long)gridDim.x * 256;
    for (; i < n4; i += stride) {
        float4 v = reinterpret_cast<const float4*>(x)[i];
        float xs[4] = {v.x, v.y, v.z, v.w};
        s4 o;
        short* op = &o.a;
        #pragma unroll
        for (int j = 0; j < 4; ++j) {
            short hb = f2bf(xs[j]);
            op[j] = LO ? f2bf(xs[j] - bf2f(hb)) : hb;
        }
        reinterpret_cast<s4*>(y)[i] = o;
    }
}

// ---------------- f32 -> bf16 hi AND lo in one pass ----------------
__global__ __launch_bounds__(256)
void cvt_both(const float* __restrict__ x, short* __restrict__ yh,
              short* __restrict__ yl, long n4)
{
    long i = (long)blockIdx.x * 256 + threadIdx.x;
    long stride = (long)gridDim.x * 256;
    for (; i < n4; i += stride) {
        float4 v = reinterpret_cast<const float4*>(x)[i];
        float xs[4] = {v.x, v.y, v.z, v.w};
        s4 oh, ol;
        short* hp = &oh.a; short* lp = &ol.a;
        #pragma unroll
        for (int j = 0; j < 4; ++j) {
            short hb = f2bf(xs[j]);
            hp[j] = hb;
            lp[j] = f2bf(xs[j] - bf2f(hb));
        }
        reinterpret_cast<s4*>(yh)[i] = oh;
        reinterpret_cast<s4*>(yl)[i] = ol;
    }
}

// ---------------- RoPE in place on q,k [S][4096] ----------------
__global__ __launch_bounds__(256)
void rope_kernel(float* __restrict__ q, float* __restrict__ k, const int* __restrict__ pos)
{
    int i = blockIdx.x * 256 + threadIdx.x;
    if (i >= 1024 * 32 * 64) return;
    int d   = i & 63;
    int rem = i >> 6;
    int h   = rem & 31;
    int s   = rem >> 5;
    float p = (float)pos[s];
    float inv = exp2f(-(float)d * (13.287712379549449f / 64.0f));
    float ang = p * inv;
    float c = cosf(ang), sn = sinf(ang);
    long base = ((long)s * 4096) + h * 128 + d;
    float x1 = q[base], x2 = q[base + 64];
    q[base]      = x1 * c - x2 * sn;
    q[base + 64] = x2 * c + x1 * sn;
    x1 = k[base]; x2 = k[base + 64];
    k[base]      = x1 * c - x2 * sn;
    k[base + 64] = x2 * c + x1 * sn;
}

// ---------------- row stats: est + LN1 scale/offset from raw scores ----------------
__global__ __launch_bounds__(256)
void row_stats(const float* __restrict__ x,
               const float* __restrict__ sw, const float* __restrict__ sbias,
               float* __restrict__ est, float* __restrict__ lnA, float* __restrict__ lnO)
{
    long row = blockIdx.x;
    const float* xr = x + row * 1024;
    __shared__ float sb[12];
    float s = 0.f, ss = 0.f, dt = 0.f;
    #pragma unroll
    for (int i = 0; i < 4; ++i) {
        int c = threadIdx.x + i * 256;
        float v = xr[c];
        s += v; ss += v * v; dt += v * sw[c];
    }
    #pragma unroll
    for (int off = 32; off; off >>= 1) {
        s  += __shfl_down(s, off, 64);
        ss += __shfl_down(ss, off, 64);
        dt += __shfl_down(dt, off, 64);
    }
    int wid = threadIdx.x >> 6, lane = threadIdx.x & 63;
    if (!lane) { sb[wid] = s; sb[4 + wid] = ss; sb[8 + wid] = dt; }
    __syncthreads();
    if (threadIdx.x == 0) {
        s  = sb[0] + sb[1] + sb[2] + sb[3];
        ss = sb[4] + sb[5] + sb[6] + sb[7];
        float mean = s * (1.f / 1024.f);
        float var  = ss * (1.f / 1024.f) - mean * mean;
        float a    = rsqrtf(var + 1e-5f);
        est[row] = sb[8] + sb[9] + sb[10] + sb[11] + sbias[0];
        lnA[row] = a;
        lnO[row] = -mean * a;
    }
}

// ---------------- conv layer 0 with LN1 fused; lnA/lnO staged in LDS ----------------
__global__ __launch_bounds__(256)
void conv_ln1(const float* __restrict__ x, float* __restrict__ y,
              const float* __restrict__ cw, const float* __restrict__ cb,
              const float* __restrict__ lnA, const float* __restrict__ lnO,
              const float* __restrict__ w1, const float* __restrict__ b1, int h0)
{
    const int S = 1024;
    int h  = blockIdx.z;
    int hg = h0 + h;
    int q0 = blockIdx.y * 64;
    int k0 = blockIdx.x * 64;
    __shared__ float ws[63];
    __shared__ float sA[126];
    __shared__ float sO[126];
    int tid = threadIdx.x;
    if (tid < 63) ws[tid] = cw[hg * 63 + tid];
    if (tid < 126) {
        int g = q0 - 62 + tid;
        const float* lA = lnA + (long)h * S;
        const float* lO = lnO + (long)h * S;
        sA[tid] = (g >= 0) ? lA[g] : 0.f;
        sO[tid] = (g >= 0) ? lO[g] : 0.f;
    }
    __syncthreads();
    int c   = tid & 63;
    int grp = tid >> 6;
    int qb  = q0 + grp * 16;
    float wc = w1[k0 + c];
    float bc = b1[k0 + c];
    const float* xh = x + (long)h * S * S + k0 + c;
    float X[78];
    #pragma unroll
    for (int j = 0; j < 78; ++j) {
        int g = qb - 62 + j;
        int rl = grp * 16 + j;
        if (g >= 0) {
            float raw = xh[(long)g * S];
            X[j] = fmaf(raw * sA[rl] + sO[rl], wc, bc);
        } else X[j] = 0.f;
    }
    float wr[63];
    #pragma unroll
    for (int t = 0; t < 63; ++t) wr[t] = ws[t];
    float bias = cb[hg];
    float* yh = y + (long)h * S * S + k0 + c;
    #pragma unroll
    for (int i = 0; i < 16; ++i) {
        float a0 = 0.f, a1 = 0.f, a2 = 0.f, a3 = 0.f;
        #pragma unroll
        for (int t = 0; t < 60; t += 4) {
            a0 += wr[t]     * X[i + t];
            a1 += wr[t + 1] * X[i + t + 1];
            a2 += wr[t + 2] * X[i + t + 2];
            a3 += wr[t + 3] * X[i + t + 3];
        }
        a0 += wr[60] * X[i + 60];
        a1 += wr[61] * X[i + 61];
        a2 += wr[62] * X[i + 62];
        float acc = bias + ((a0 + a1) + (a2 + a3));
        yh[(long)(qb + i) * S] = fmaxf(acc, 0.f);
    }
}

// ---------------- causal depthwise conv + ReLU, register-tap (layers 1,2) ----------------
__global__ __launch_bounds__(256)
void conv_fast(const float* __restrict__ x, float* __restrict__ y,
               const float* __restrict__ cw, const float* __restrict__ cb,
               int layer, int h0)
{
    const int S = 1024;
    int h  = blockIdx.z;
    int hg = h0 + h;
    int q0 = blockIdx.y * 64;
    int k0 = blockIdx.x * 64;
    __shared__ float ws[63];
    if (threadIdx.x < 63) ws[threadIdx.x] = cw[(layer * 32 + hg) * 63 + threadIdx.x];
    __syncthreads();
    int c   = threadIdx.x & 63;
    int grp = threadIdx.x >> 6;
    int qb  = q0 + grp * 16;
    const float* xh = x + (long)h * S * S + k0 + c;
    float X[78];
    #pragma unroll
    for (int j = 0; j < 78; ++j) {
        int g = qb - 62 + j;
        X[j] = (g >= 0) ? xh[(long)g * S] : 0.f;
    }
    float wr[63];
    #pragma unroll
    for (int t = 0; t < 63; ++t) wr[t] = ws[t];
    float bias = cb[layer * 32 + hg];
    float* yh = y + (long)h * S * S + k0 + c;
    #pragma unroll
    for (int i = 0; i < 16; ++i) {
        float a0 = 0.f, a1 = 0.f, a2 = 0.f, a3 = 0.f;
        #pragma unroll
        for (int t = 0; t < 60; t += 4) {
            a0 += wr[t]     * X[i + t];
            a1 += wr[t + 1] * X[i + t + 1];
            a2 += wr[t + 2] * X[i + t + 2];
            a3 += wr[t + 3] * X[i + t + 3];
        }
        a0 += wr[60] * X[i + 60];
        a1 += wr[61] * X[i + 61];
        a2 += wr[62] * X[i + 62];
        float acc = bias + ((a0 + a1) + (a2 + a3));
        yh[(long)(qb + i) * S] = fmaxf(acc, 0.f);
    }
}

// ---------------- fused LayerNorm2 + mask + softmax + sigmoid gate -> bf16 p ----------------
__global__ __launch_bounds__(256)
void ln2_softmax(const float* __restrict__ x, __hip_bfloat16* __restrict__ pb,
                 const float* __restrict__ w, const float* __restrict__ b,
                 const float* __restrict__ mask, const float* __restrict__ est)
{
    const int S = 1024;
    long row = blockIdx.x;
    int q = (int)(row & (S - 1));
    const float* xr = x + row * 1024;
    const float* mrow = mask + (long)q * S;
    __shared__ float sb[8];
    float v[4];
    float s = 0.f, ss = 0.f;
    #pragma unroll
    for (int i = 0; i < 4; ++i) {
        int c = threadIdx.x + i * 256;
        v[i] = xr[c];
        s += v[i]; ss += v[i] * v[i];
    }
    #pragma unroll
    for (int off = 32; off; off >>= 1) {
        s  += __shfl_down(s, off, 64);
        ss += __shfl_down(ss, off, 64);
    }
    int wid = threadIdx.x >> 6, lane = threadIdx.x & 63;
    if (!lane) { sb[wid] = s; sb[4 + wid] = ss; }
    __syncthreads();
    s  = sb[0] + sb[1] + sb[2] + sb[3];
    ss = sb[4] + sb[5] + sb[6] + sb[7];
    float mean = s * (1.f / 1024.f);
    float var  = ss * (1.f / 1024.f) - mean * mean;
    float inv  = rsqrtf(var + 1e-5f);
    const float FMIN = -3.4028235e38f;
    float mx = FMIN;
    #pragma unroll
    for (int i = 0; i < 4; ++i) {
        int c = threadIdx.x + i * 256;
        float t = (v[i] - mean) * inv * w[c] + b[c] + mrow[c];
        t = fmaxf(t, FMIN);
        v[i] = t;
        mx = fmaxf(mx, t);
    }
    #pragma unroll
    for (int off = 32; off; off >>= 1) mx = fmaxf(mx, __shfl_down(mx, off, 64));
    __syncthreads();
    if (!lane) sb[wid] = mx;
    __syncthreads();
    mx = fmaxf(fmaxf(sb[0], sb[1]), fmaxf(sb[2], sb[3]));
    float s2 = 0.f;
    #pragma unroll
    for (int i = 0; i < 4; ++i) { v[i] = expf(v[i] - mx); s2 += v[i]; }
    #pragma unroll
    for (int off = 32; off; off >>= 1) s2 += __shfl_down(s2, off, 64);
    __syncthreads();
    if (!lane) sb[4 + wid] = s2;
    __syncthreads();
    s2 = sb[4] + sb[5] + sb[6] + sb[7];
    float e = est[row];
    float sc = (1.f / (1.f + expf(-e))) / s2;
    __hip_bfloat16* pr = pb + row * S;
    #pragma unroll
    for (int i = 0; i < 4; ++i) {
        int c = threadIdx.x + i * 256;
        pr[c] = __float2bfloat16(v[i] * sc);
    }
}

extern "C" void kernel_launch(void* const* d_in, const int* in_sizes, int n_in,
                              void* d_out, int out_size, void* d_ws, size_t ws_size,
                              hipStream_t stream) {
    const int S = 1024, H = 32, HID = 4096, DH = 128, DL = 64;

    const float* hs   = (const float*)d_in[0];
    const float* mask = (const float*)d_in[1];
    const int*   pos  = (const int*)d_in[2];
    const float* Wq   = (const float*)d_in[3];
    const float* Wk   = (const float*)d_in[4];
    const float* Wv   = (const float*)d_in[5];
    const float* Wo   = (const float*)d_in[6];
    const float* Wdq  = (const float*)d_in[7];
    const float* Wdk  = (const float*)d_in[8];
    const float* ln1w = (const float*)d_in[9];
    const float* ln1b = (const float*)d_in[10];
    const float* ln2w = (const float*)d_in[11];
    const float* ln2b = (const float*)d_in[12];
    const float* cw   = (const float*)d_in[13];
    const float* cb   = (const float*)d_in[14];
    const float* sw   = (const float*)d_in[15];
    const float* sbia = (const float*)d_in[16];
    float* out = (float*)d_out;

    // ---- workspace: minimize loop-live fixed footprint ----
    float* p   = (float*)d_ws;
    float* ql  = p; p += (long)H * S * DL;
    float* kl  = p; p += (long)H * S * DL;
    float* est = p; p += (long)H * S;
    float* lnA = p; p += (long)H * S;
    float* lnO = p; p += (long)H * S;
    short* hsH = (short*)p; p += (long)S * HID / 2;   // later aoH (PV out bf16)
    short* hsL = (short*)p; p += (long)S * HID / 2;   // later vT bf16 [H][128][1024]
    float* region = p;                                 // everything else
    float* qb  = region;
    float* kb  = qb + (long)S * HID;
    short* WbH = (short*)(kb + (long)S * HID);
    short* WbL = WbH + (long)HID * HID;
    short* aoH = hsH;
    short* vT  = hsL;

    long wsFloats     = (long)(ws_size / 4);
    long regionFloats = wsFloats - (region - (float*)d_ws);
    long perHead      = 2L * S * S;                    // sc0 + sc1 fp32
    int CH = (int)(regionFloats / perHead);
    if (CH > H) CH = H;
    if (CH < 1) CH = 1;
    int iters = (H + CH - 1) / CH;
    CH = (H + iters - 1) / iters;                      // even chunks
    float* sc0 = region;
    float* sc1 = sc0 + (long)CH * S * S;
    __hip_bfloat16* pb = (__hip_bfloat16*)sc0;         // alias: sc0 dead after conv3

    dim3 blk(256);
    long n4_hs = (long)S * HID / 4, n4_W = (long)HID * HID / 4;
    size_t projBytes = (size_t)S * HID * sizeof(float);

    // hs -> hi/lo bf16
    cvt_both<<<2048, blk, 0, stream>>>(hs, hsH, hsL, n4_hs);

    // ---- Q projection: 3 terms x 2 K-chunks (z=6, kSteps=64) — round-7 proven config ----
    (void)hipMemsetAsync(qb, 0, projBytes, stream);
    cvt_both<<<2048, blk, 0, stream>>>(Wq, WbH, WbL, n4_W);
    gemm16_sk<<<dim3(HID / 128, S / 128, 6), blk, 0, stream>>>(
        (__hip_bfloat16*)hsH, (__hip_bfloat16*)hsL, (__hip_bfloat16*)hsH, HID,
        (__hip_bfloat16*)WbH, (__hip_bfloat16*)WbH, (__hip_bfloat16*)WbL, HID,
        qb, HID, 64, 2, 1.f);

    // ---- K projection ----
    (void)hipMemsetAsync(kb, 0, projBytes, stream);
    cvt_both<<<2048, blk, 0, stream>>>(Wk, WbH, WbL, n4_W);
    gemm16_sk<<<dim3(HID / 128, S / 128, 6), blk, 0, stream>>>(
        (__hip_bfloat16*)hsH, (__hip_bfloat16*)hsL, (__hip_bfloat16*)hsH, HID,
        (__hip_bfloat16*)WbH, (__hip_bfloat16*)WbH, (__hip_bfloat16*)WbL, HID,
        kb, HID, 64, 2, 1.f);

    // ---- V projection: hi-only, writes vT bf16 (overwrites hsL) ----
    cvt_part<false><<<2048, blk, 0, stream>>>(Wv, WbH, n4_W);
    gemm16<2><<<dim3(HID / 128, S / 128, 1), blk, 0, stream>>>(
        (__hip_bfloat16*)hsH, HID, 0, (__hip_bfloat16*)WbH, HID, 0, vT, S, 0, HID, 1.f);

    rope_kernel<<<(S * H * 64 + 255) / 256, blk, 0, stream>>>(qb, kb, pos);

    // low-rank down-proj (fp32 VALU, exact)
    gemm_f32<true><<<dim3(1, S / 64, H), blk, 0, stream>>>(qb, HID, 128, Wdq, DH, 0, ql, DL, (long)S * DL, S, DL, DH, 1.f);
    gemm_f32<true><<<dim3(1, S / 64, H), blk, 0, stream>>>(kb, HID, 128, Wdk, DH, 0, kl, DL, (long)S * DL, S, DL, DH, 1.f);
    // qb/kb/WbH/WbL now dead -> region becomes the score area

    for (int c0 = 0; c0 < H; c0 += CH) {
        int ch = (c0 + CH <= H) ? CH : (H - c0);
        gemm_s<<<dim3(S / 128, S / 128, ch), blk, 0, stream>>>(
            ql + (long)c0 * S * DL, DL, (long)S * DL,
            kl + (long)c0 * S * DL, DL, (long)S * DL,
            sc0, S, (long)S * S, DL, 0.125f);
        row_stats<<<ch * S, blk, 0, stream>>>(sc0, sw, sbia,
            est + (long)c0 * S, lnA + (long)c0 * S, lnO + (long)c0 * S);
        conv_ln1<<<dim3(16, 16, ch), blk, 0, stream>>>(sc0, sc1, cw, cb,
            lnA + (long)c0 * S, lnO + (long)c0 * S, ln1w, ln1b, c0);
        conv_fast<<<dim3(16, 16, ch), blk, 0, stream>>>(sc1, sc0, cw, cb, 1, c0);
        conv_fast<<<dim3(16, 16, ch), blk, 0, stream>>>(sc0, sc1, cw, cb, 2, c0);
        ln2_softmax<<<ch * S, blk, 0, stream>>>(sc1, pb, ln2w, ln2b, mask, est + (long)c0 * S);
        // PV: 64x128 tiles, grid 16 x ch
        gemm_pv<<<dim3(S / 64, ch), blk, 0, stream>>>(
            pb, (long)S * S,
            (__hip_bfloat16*)(vT + (long)c0 * DH * S), (long)DH * S,
            (__hip_bfloat16*)(aoH + (long)c0 * 128), HID, 128);
    }

    // ---- final: out = aoH @ Wo^T (hi-only bf16, split-K atomic, z=2) ----
    short* WoH = (short*)region;   // scores dead after last PV
    cvt_part<false><<<2048, blk, 0, stream>>>(Wo, WoH, n4_W);
    (void)hipMemsetAsync(out, 0, projBytes, stream);
    gemm16_sk<<<dim3(HID / 128, S / 128, 2), blk, 0, stream>>>(
        (__hip_bfloat16*)aoH, (__hip_bfloat16*)aoH, (__hip_bfloat16*)aoH, HID,
        (__hip_bfloat16*)WoH, (__hip_bfloat16*)WoH, (__hip_bfloat16*)WoH, HID,
        out, HID, 64, 2, 1.f);
}

// Round 13
// 1128.579 us; speedup vs baseline: 1.2531x; 1.1733x over previous
//
#include <hip/hip_runtime.h>
#include <hip/hip_bf16.h>

typedef __attribute__((ext_vector_type(8))) short bf16x8;
typedef __attribute__((ext_vector_type(4))) float f32x4;

#define TILE 64
#define TK 16

__device__ inline short f2bf(float x) {
    unsigned u = __float_as_uint(x);
    unsigned r = (u + 0x7fffu + ((u >> 16) & 1u)) >> 16;
    return (short)r;
}
__device__ inline float bf2f(short h) {
    return __uint_as_float(((unsigned)(unsigned short)h) << 16);
}

// ---------------- fp32 VALU GEMM (down-proj only): C = A * B^T ----------------
template<bool BT>
__global__ __launch_bounds__(256)
void gemm_f32(const float* __restrict__ A, int lda, long sA,
              const float* __restrict__ B, int ldb, long sB,
              float* __restrict__ C, int ldc, long sC,
              int M, int N, int Kd, float alpha)
{
    long bz = blockIdx.z;
    A += bz * sA; B += bz * sB; C += bz * sC;
    int m0 = blockIdx.y * TILE, n0 = blockIdx.x * TILE;
    __shared__ float As[TK][TILE + 4];
    __shared__ float Bs[TK][TILE + 4];
    int tid = threadIdx.x;
    int tm = (tid >> 4) * 4;
    int tn = (tid & 15) * 4;
    float acc[4][4] = {};
    for (int k0 = 0; k0 < Kd; k0 += TK) {
        {
            int kk = tid & 15;
            int m  = tid >> 4;
            #pragma unroll
            for (int mm = 0; mm < 4; ++mm)
                As[kk][m + mm * 16] = A[(long)(m0 + m + mm * 16) * lda + k0 + kk];
        }
        {
            int kk = tid & 15;
            int n  = tid >> 4;
            #pragma unroll
            for (int nn = 0; nn < 4; ++nn)
                Bs[kk][n + nn * 16] = B[(long)(n0 + n + nn * 16) * ldb + k0 + kk];
        }
        __syncthreads();
        #pragma unroll
        for (int kk = 0; kk < TK; ++kk) {
            float4 a4 = *reinterpret_cast<const float4*>(&As[kk][tm]);
            float4 b4 = *reinterpret_cast<const float4*>(&Bs[kk][tn]);
            float a[4] = {a4.x, a4.y, a4.z, a4.w};
            float b[4] = {b4.x, b4.y, b4.z, b4.w};
            #pragma unroll
            for (int i = 0; i < 4; ++i)
                #pragma unroll
                for (int j = 0; j < 4; ++j)
                    acc[i][j] += a[i] * b[j];
        }
        __syncthreads();
    }
    #pragma unroll
    for (int i = 0; i < 4; ++i)
        #pragma unroll
        for (int j = 0; j < 4; ++j)
            C[(long)(m0 + tm + i) * ldc + n0 + tn + j] = alpha * acc[i][j];
}

// ---------------- m97-style bf16 MFMA GEMM: C (+)= alpha * A * B^T ----------------
// CMODE 0: C fp32 =, 1: C fp32 +=, 2: C^T bf16 (CT[n][m]), 3: C bf16 =
__device__ inline void gld_lds16(const __hip_bfloat16* g, __hip_bfloat16* l)
{
    __builtin_amdgcn_global_load_lds(
        (const __attribute__((address_space(1))) unsigned int*)g,
        (__attribute__((address_space(3))) unsigned int*)l,
        16, 0, 0);
}

template<int CMODE>
__global__ __launch_bounds__(256)
void gemm16(const __hip_bfloat16* __restrict__ A, int lda, long sA,
            const __hip_bfloat16* __restrict__ B, int ldb, long sB,
            void* __restrict__ Cv, int ldc, long sC,
            int Kd, float alpha)
{
    __shared__ __hip_bfloat16 As[128][32];
    __shared__ __hip_bfloat16 Bs[128][32];
    long bz = blockIdx.z;
    A += bz * sA; B += bz * sB;
    int m0 = blockIdx.y * 128, n0 = blockIdx.x * 128;
    int tid  = threadIdx.x;
    int w    = tid >> 6, lane = tid & 63;
    int wm   = w >> 1,  wn   = w & 1;
    int lrow = lane >> 2;
    int lseg = (lane & 3) * 8;
    int fr   = lane & 15;
    int kg   = (lane >> 4) * 8;
    f32x4 acc[4][4] = {};
    for (int k0 = 0; k0 < Kd; k0 += 32) {
        #pragma unroll
        for (int i = 0; i < 2; ++i) {
            int r = w * 32 + i * 16;
            gld_lds16(&A[(long)(m0 + r + lrow) * lda + k0 + lseg], &As[r][0]);
            gld_lds16(&B[(long)(n0 + r + lrow) * ldb + k0 + lseg], &Bs[r][0]);
        }
        __syncthreads();
        bf16x8 af[4], bfr[4];
        #pragma unroll
        for (int m = 0; m < 4; ++m)
            af[m] = *(const bf16x8*)&As[wm * 64 + m * 16 + fr][kg];
        #pragma unroll
        for (int n = 0; n < 4; ++n)
            bfr[n] = *(const bf16x8*)&Bs[wn * 64 + n * 16 + fr][kg];
        #pragma unroll
        for (int m = 0; m < 4; ++m)
            #pragma unroll
            for (int n = 0; n < 4; ++n)
                acc[m][n] = __builtin_amdgcn_mfma_f32_16x16x32_bf16(af[m], bfr[n], acc[m][n], 0, 0, 0);
        __syncthreads();
    }
    int crow0 = (lane >> 4) * 4;
    if constexpr (CMODE == 2) {
        __hip_bfloat16* CT = (__hip_bfloat16*)Cv + bz * sC;
        #pragma unroll
        for (int m = 0; m < 4; ++m)
            #pragma unroll
            for (int n = 0; n < 4; ++n)
                #pragma unroll
                for (int r = 0; r < 4; ++r) {
                    int row = m0 + wm * 64 + m * 16 + crow0 + r;
                    int col = n0 + wn * 64 + n * 16 + fr;
                    CT[(long)col * ldc + row] = __float2bfloat16(alpha * acc[m][n][r]);
                }
    } else if constexpr (CMODE == 3) {
        __hip_bfloat16* C = (__hip_bfloat16*)Cv + bz * sC;
        #pragma unroll
        for (int m = 0; m < 4; ++m)
            #pragma unroll
            for (int n = 0; n < 4; ++n)
                #pragma unroll
                for (int r = 0; r < 4; ++r)
                    C[(long)(m0 + wm * 64 + m * 16 + crow0 + r) * ldc
                      + n0 + wn * 64 + n * 16 + fr] = __float2bfloat16(alpha * acc[m][n][r]);
    } else {
        float* C = (float*)Cv + bz * sC;
        #pragma unroll
        for (int m = 0; m < 4; ++m)
            #pragma unroll
            for (int n = 0; n < 4; ++n)
                #pragma unroll
                for (int r = 0; r < 4; ++r) {
                    long idx = (long)(m0 + wm * 64 + m * 16 + crow0 + r) * ldc
                             + n0 + wn * 64 + n * 16 + fr;
                    float v = alpha * acc[m][n][r];
                    if constexpr (CMODE == 1) v += C[idx];
                    C[idx] = v;
                }
    }
}

// ---------------- split-K/term bf16 MFMA GEMM with atomic accumulate ----------------
__global__ __launch_bounds__(256)
void gemm16_sk(const __hip_bfloat16* __restrict__ A0, const __hip_bfloat16* __restrict__ A1,
               const __hip_bfloat16* __restrict__ A2, int lda,
               const __hip_bfloat16* __restrict__ B0, const __hip_bfloat16* __restrict__ B1,
               const __hip_bfloat16* __restrict__ B2, int ldb,
               float* __restrict__ C, int ldc,
               int kSteps, int chunksPerTerm, float alpha)
{
    __shared__ __hip_bfloat16 As[128][32];
    __shared__ __hip_bfloat16 Bs[128][32];
    int z    = blockIdx.z;
    int term = z / chunksPerTerm;
    int sub  = z - term * chunksPerTerm;
    const __hip_bfloat16* A = (term == 0) ? A0 : (term == 1) ? A1 : A2;
    const __hip_bfloat16* B = (term == 0) ? B0 : (term == 1) ? B1 : B2;
    int kbase = sub * kSteps * 32;
    int m0 = blockIdx.y * 128, n0 = blockIdx.x * 128;
    int tid  = threadIdx.x;
    int w    = tid >> 6, lane = tid & 63;
    int wm   = w >> 1,  wn   = w & 1;
    int lrow = lane >> 2;
    int lseg = (lane & 3) * 8;
    int fr   = lane & 15;
    int kg   = (lane >> 4) * 8;
    f32x4 acc[4][4] = {};
    for (int it = 0; it < kSteps; ++it) {
        int k0 = kbase + it * 32;
        #pragma unroll
        for (int i = 0; i < 2; ++i) {
            int r = w * 32 + i * 16;
            gld_lds16(&A[(long)(m0 + r + lrow) * lda + k0 + lseg], &As[r][0]);
            gld_lds16(&B[(long)(n0 + r + lrow) * ldb + k0 + lseg], &Bs[r][0]);
        }
        __syncthreads();
        bf16x8 af[4], bfr[4];
        #pragma unroll
        for (int m = 0; m < 4; ++m)
            af[m] = *(const bf16x8*)&As[wm * 64 + m * 16 + fr][kg];
        #pragma unroll
        for (int n = 0; n < 4; ++n)
            bfr[n] = *(const bf16x8*)&Bs[wn * 64 + n * 16 + fr][kg];
        #pragma unroll
        for (int m = 0; m < 4; ++m)
            #pragma unroll
            for (int n = 0; n < 4; ++n)
                acc[m][n] = __builtin_amdgcn_mfma_f32_16x16x32_bf16(af[m], bfr[n], acc[m][n], 0, 0, 0);
        __syncthreads();
    }
    int crow0 = (lane >> 4) * 4;
    #pragma unroll
    for (int m = 0; m < 4; ++m)
        #pragma unroll
        for (int n = 0; n < 4; ++n)
            #pragma unroll
            for (int r = 0; r < 4; ++r) {
                long idx = (long)(m0 + wm * 64 + m * 16 + crow0 + r) * ldc
                         + n0 + wn * 64 + n * 16 + fr;
                atomicAdd(&C[idx], alpha * acc[m][n][r]);
            }
}

// ---------------- PV GEMM, 64x128 tile: aoH bf16 = pb * vT^T ----------------
__global__ __launch_bounds__(256)
void gemm_pv(const __hip_bfloat16* __restrict__ Ab, long sA,
             const __hip_bfloat16* __restrict__ Bb, long sB,
             __hip_bfloat16* __restrict__ C, int ldc, long sC)
{
    __shared__ __hip_bfloat16 As[64][32];
    __shared__ __hip_bfloat16 Bs[128][32];
    const int S = 1024;
    int h  = blockIdx.y;
    const __hip_bfloat16* A = Ab + (long)h * sA;
    const __hip_bfloat16* B = Bb + (long)h * sB;
    __hip_bfloat16* Ch = C + (long)h * sC;
    int m0 = blockIdx.x * 64;
    int tid  = threadIdx.x;
    int w    = tid >> 6, lane = tid & 63;
    int wm   = w >> 1,  wn   = w & 1;
    int lrow = lane >> 2;
    int lseg = (lane & 3) * 8;
    int fr   = lane & 15;
    int kg   = (lane >> 4) * 8;
    f32x4 acc[2][4] = {};
    for (int k0 = 0; k0 < S; k0 += 32) {
        gld_lds16(&A[(long)(m0 + w * 16 + lrow) * S + k0 + lseg], &As[w * 16][0]);
        #pragma unroll
        for (int i = 0; i < 2; ++i) {
            int r = w * 32 + i * 16;
            gld_lds16(&B[(long)(r + lrow) * S + k0 + lseg], &Bs[r][0]);
        }
        __syncthreads();
        bf16x8 af[2], bfr[4];
        #pragma unroll
        for (int m = 0; m < 2; ++m)
            af[m] = *(const bf16x8*)&As[wm * 32 + m * 16 + fr][kg];
        #pragma unroll
        for (int n = 0; n < 4; ++n)
            bfr[n] = *(const bf16x8*)&Bs[wn * 64 + n * 16 + fr][kg];
        #pragma unroll
        for (int m = 0; m < 2; ++m)
            #pragma unroll
            for (int n = 0; n < 4; ++n)
                acc[m][n] = __builtin_amdgcn_mfma_f32_16x16x32_bf16(af[m], bfr[n], acc[m][n], 0, 0, 0);
        __syncthreads();
    }
    int crow0 = (lane >> 4) * 4;
    #pragma unroll
    for (int m = 0; m < 2; ++m)
        #pragma unroll
        for (int n = 0; n < 4; ++n)
            #pragma unroll
            for (int r = 0; r < 4; ++r)
                Ch[(long)(m0 + wm * 32 + m * 16 + crow0 + r) * ldc
                   + wn * 64 + n * 16 + fr] = __float2bfloat16(acc[m][n][r]);
}

// ---------------- in-register split MFMA GEMM (QK^T): C = alpha * A * B^T ----------------
#define LP 40
__global__ __launch_bounds__(256)
void gemm_s(const float* __restrict__ A, int lda, long sA,
            const float* __restrict__ B, int ldb, long sB,
            float* __restrict__ C, int ldc, long sC,
            int Kd, float alpha)
{
    __shared__ short Ah[128][LP];
    __shared__ short Bh[128][LP];
    __shared__ short Al[128][LP];
    __shared__ short Bl[128][LP];
    long bz = blockIdx.z;
    A += bz * sA; B += bz * sB; C += bz * sC;
    int m0 = blockIdx.y * 128, n0 = blockIdx.x * 128;
    int tid  = threadIdx.x;
    int lane = tid & 63;
    int w    = tid >> 6;
    int wm   = w >> 1, wn = w & 1;
    int srow = tid >> 1;
    int scol = (tid & 1) * 16;
    int fr   = lane & 15;
    int kg   = (lane >> 4) * 8;
    f32x4 acc[4][4] = {};
    for (int k0 = 0; k0 < Kd; k0 += 32) {
        #pragma unroll
        for (int ab = 0; ab < 2; ++ab) {
            const float* src = ab ? (B + (long)(n0 + srow) * ldb + k0 + scol)
                                  : (A + (long)(m0 + srow) * lda + k0 + scol);
            short* dh = ab ? &Bh[srow][scol] : &Ah[srow][scol];
            short* dl = ab ? &Bl[srow][scol] : &Al[srow][scol];
            #pragma unroll
            for (int half = 0; half < 2; ++half) {
                float4 x0 = *reinterpret_cast<const float4*>(src + half * 8);
                float4 x1 = *reinterpret_cast<const float4*>(src + half * 8 + 4);
                float xs[8] = {x0.x, x0.y, x0.z, x0.w, x1.x, x1.y, x1.z, x1.w};
                bf16x8 hv, lv;
                #pragma unroll
                for (int j = 0; j < 8; ++j) {
                    short hb = f2bf(xs[j]);
                    hv[j] = hb;
                    lv[j] = f2bf(xs[j] - bf2f(hb));
                }
                *reinterpret_cast<bf16x8*>(dh + half * 8) = hv;
                *reinterpret_cast<bf16x8*>(dl + half * 8) = lv;
            }
        }
        __syncthreads();
        bf16x8 afh[4], bfh[4], afl[4], bfl[4];
        #pragma unroll
        for (int m = 0; m < 4; ++m) {
            afh[m] = *(const bf16x8*)&Ah[wm * 64 + m * 16 + fr][kg];
            afl[m] = *(const bf16x8*)&Al[wm * 64 + m * 16 + fr][kg];
        }
        #pragma unroll
        for (int n = 0; n < 4; ++n) {
            bfh[n] = *(const bf16x8*)&Bh[wn * 64 + n * 16 + fr][kg];
            bfl[n] = *(const bf16x8*)&Bl[wn * 64 + n * 16 + fr][kg];
        }
        #pragma unroll
        for (int m = 0; m < 4; ++m)
            #pragma unroll
            for (int n = 0; n < 4; ++n) {
                acc[m][n] = __builtin_amdgcn_mfma_f32_16x16x32_bf16(afh[m], bfh[n], acc[m][n], 0, 0, 0);
                acc[m][n] = __builtin_amdgcn_mfma_f32_16x16x32_bf16(afh[m], bfl[n], acc[m][n], 0, 0, 0);
                acc[m][n] = __builtin_amdgcn_mfma_f32_16x16x32_bf16(afl[m], bfh[n], acc[m][n], 0, 0, 0);
            }
        __syncthreads();
    }
    int crow0 = (lane >> 4) * 4;
    #pragma unroll
    for (int m = 0; m < 4; ++m)
        #pragma unroll
        for (int n = 0; n < 4; ++n)
            #pragma unroll
            for (int r = 0; r < 4; ++r)
                C[(long)(m0 + wm * 64 + m * 16 + crow0 + r) * ldc
                  + n0 + wn * 64 + n * 16 + fr] = alpha * acc[m][n][r];
}

// ---------------- f32 -> bf16 hi or lo part (n4 = n/4) ----------------
struct alignas(8) s4 { short a, b, c, d; };
template<bool LO>
__global__ __launch_bounds__(256)
void cvt_part(const float* __restrict__ x, short* __restrict__ y, long n4)
{
    long i = (long)blockIdx.x * 256 + threadIdx.x;
    long stride = (long)gridDim.x * 256;
    for (; i < n4; i += stride) {
        float4 v = reinterpret_cast<const float4*>(x)[i];
        float xs[4] = {v.x, v.y, v.z, v.w};
        s4 o;
        short* op = &o.a;
        #pragma unroll
        for (int j = 0; j < 4; ++j) {
            short hb = f2bf(xs[j]);
            op[j] = LO ? f2bf(xs[j] - bf2f(hb)) : hb;
        }
        reinterpret_cast<s4*>(y)[i] = o;
    }
}

// ---------------- f32 -> bf16 hi AND lo in one pass ----------------
__global__ __launch_bounds__(256)
void cvt_both(const float* __restrict__ x, short* __restrict__ yh,
              short* __restrict__ yl, long n4)
{
    long i = (long)blockIdx.x * 256 + threadIdx.x;
    long stride = (long)gridDim.x * 256;
    for (; i < n4; i += stride) {
        float4 v = reinterpret_cast<const float4*>(x)[i];
        float xs[4] = {v.x, v.y, v.z, v.w};
        s4 oh, ol;
        short* hp = &oh.a; short* lp = &ol.a;
        #pragma unroll
        for (int j = 0; j < 4; ++j) {
            short hb = f2bf(xs[j]);
            hp[j] = hb;
            lp[j] = f2bf(xs[j] - bf2f(hb));
        }
        reinterpret_cast<s4*>(yh)[i] = oh;
        reinterpret_cast<s4*>(yl)[i] = ol;
    }
}

// ---------------- RoPE in place on q,k [S][4096] ----------------
__global__ __launch_bounds__(256)
void rope_kernel(float* __restrict__ q, float* __restrict__ k, const int* __restrict__ pos)
{
    int i = blockIdx.x * 256 + threadIdx.x;
    if (i >= 1024 * 32 * 64) return;
    int d   = i & 63;
    int rem = i >> 6;
    int h   = rem & 31;
    int s   = rem >> 5;
    float p = (float)pos[s];
    float inv = exp2f(-(float)d * (13.287712379549449f / 64.0f));
    float ang = p * inv;
    float c = cosf(ang), sn = sinf(ang);
    long base = ((long)s * 4096) + h * 128 + d;
    float x1 = q[base], x2 = q[base + 64];
    q[base]      = x1 * c - x2 * sn;
    q[base + 64] = x2 * c + x1 * sn;
    x1 = k[base]; x2 = k[base + 64];
    k[base]      = x1 * c - x2 * sn;
    k[base + 64] = x2 * c + x1 * sn;
}

// ---------------- fused est + LayerNorm1: sc0 -> sc1, est (round-7 proven) ----------------
__global__ __launch_bounds__(256)
void est_ln1(const float* __restrict__ x, float* __restrict__ y,
             const float* __restrict__ sw, const float* __restrict__ sbias,
             float* __restrict__ est,
             const float* __restrict__ w, const float* __restrict__ b)
{
    long row = blockIdx.x;
    const float* xr = x + row * 1024;
    float* yr = y + row * 1024;
    __shared__ float sb[12];
    float v[4];
    float s = 0.f, ss = 0.f, dt = 0.f;
    #pragma unroll
    for (int i = 0; i < 4; ++i) {
        int c = threadIdx.x + i * 256;
        v[i] = xr[c];
        s += v[i]; ss += v[i] * v[i]; dt += v[i] * sw[c];
    }
    #pragma unroll
    for (int off = 32; off; off >>= 1) {
        s  += __shfl_down(s, off, 64);
        ss += __shfl_down(ss, off, 64);
        dt += __shfl_down(dt, off, 64);
    }
    int wid = threadIdx.x >> 6, lane = threadIdx.x & 63;
    if (!lane) { sb[wid] = s; sb[4 + wid] = ss; sb[8 + wid] = dt; }
    __syncthreads();
    s  = sb[0] + sb[1] + sb[2] + sb[3];
    ss = sb[4] + sb[5] + sb[6] + sb[7];
    if (threadIdx.x == 0) est[row] = sb[8] + sb[9] + sb[10] + sb[11] + sbias[0];
    float mean = s * (1.f / 1024.f);
    float var  = ss * (1.f / 1024.f) - mean * mean;
    float inv  = rsqrtf(var + 1e-5f);
    #pragma unroll
    for (int i = 0; i < 4; ++i) {
        int c = threadIdx.x + i * 256;
        yr[c] = (v[i] - mean) * inv * w[c] + b[c];
    }
}

// ---------------- causal depthwise conv + ReLU, register-tap ----------------
__global__ __launch_bounds__(256)
void conv_fast(const float* __restrict__ x, float* __restrict__ y,
               const float* __restrict__ cw, const float* __restrict__ cb,
               int layer, int h0)
{
    const int S = 1024;
    int h  = blockIdx.z;
    int hg = h0 + h;
    int q0 = blockIdx.y * 64;
    int k0 = blockIdx.x * 64;
    __shared__ float ws[63];
    if (threadIdx.x < 63) ws[threadIdx.x] = cw[(layer * 32 + hg) * 63 + threadIdx.x];
    __syncthreads();
    int c   = threadIdx.x & 63;
    int grp = threadIdx.x >> 6;
    int qb  = q0 + grp * 16;
    const float* xh = x + (long)h * S * S + k0 + c;
    float X[78];
    #pragma unroll
    for (int j = 0; j < 78; ++j) {
        int g = qb - 62 + j;
        X[j] = (g >= 0) ? xh[(long)g * S] : 0.f;
    }
    float wr[63];
    #pragma unroll
    for (int t = 0; t < 63; ++t) wr[t] = ws[t];
    float bias = cb[layer * 32 + hg];
    float* yh = y + (long)h * S * S + k0 + c;
    #pragma unroll
    for (int i = 0; i < 16; ++i) {
        float a0 = 0.f, a1 = 0.f, a2 = 0.f, a3 = 0.f;
        #pragma unroll
        for (int t = 0; t < 60; t += 4) {
            a0 += wr[t]     * X[i + t];
            a1 += wr[t + 1] * X[i + t + 1];
            a2 += wr[t + 2] * X[i + t + 2];
            a3 += wr[t + 3] * X[i + t + 3];
        }
        a0 += wr[60] * X[i + 60];
        a1 += wr[61] * X[i + 61];
        a2 += wr[62] * X[i + 62];
        float acc = bias + ((a0 + a1) + (a2 + a3));
        yh[(long)(qb + i) * S] = fmaxf(acc, 0.f);
    }
}

// ---------------- fused LayerNorm2 + mask + softmax + sigmoid gate -> bf16 p ----------------
__global__ __launch_bounds__(256)
void ln2_softmax(const float* __restrict__ x, __hip_bfloat16* __restrict__ pb,
                 const float* __restrict__ w, const float* __restrict__ b,
                 const float* __restrict__ mask, const float* __restrict__ est)
{
    const int S = 1024;
    long row = blockIdx.x;
    int q = (int)(row & (S - 1));
    const float* xr = x + row * 1024;
    const float* mrow = mask + (long)q * S;
    __shared__ float sb[8];
    float v[4];
    float s = 0.f, ss = 0.f;
    #pragma unroll
    for (int i = 0; i < 4; ++i) {
        int c = threadIdx.x + i * 256;
        v[i] = xr[c];
        s += v[i]; ss += v[i] * v[i];
    }
    #pragma unroll
    for (int off = 32; off; off >>= 1) {
        s  += __shfl_down(s, off, 64);
        ss += __shfl_down(ss, off, 64);
    }
    int wid = threadIdx.x >> 6, lane = threadIdx.x & 63;
    if (!lane) { sb[wid] = s; sb[4 + wid] = ss; }
    __syncthreads();
    s  = sb[0] + sb[1] + sb[2] + sb[3];
    ss = sb[4] + sb[5] + sb[6] + sb[7];
    float mean = s * (1.f / 1024.f);
    float var  = ss * (1.f / 1024.f) - mean * mean;
    float inv  = rsqrtf(var + 1e-5f);
    const float FMIN = -3.4028235e38f;
    float mx = FMIN;
    #pragma unroll
    for (int i = 0; i < 4; ++i) {
        int c = threadIdx.x + i * 256;
        float t = (v[i] - mean) * inv * w[c] + b[c] + mrow[c];
        t = fmaxf(t, FMIN);
        v[i] = t;
        mx = fmaxf(mx, t);
    }
    #pragma unroll
    for (int off = 32; off; off >>= 1) mx = fmaxf(mx, __shfl_down(mx, off, 64));
    __syncthreads();
    if (!lane) sb[wid] = mx;
    __syncthreads();
    mx = fmaxf(fmaxf(sb[0], sb[1]), fmaxf(sb[2], sb[3]));
    float s2 = 0.f;
    #pragma unroll
    for (int i = 0; i < 4; ++i) { v[i] = expf(v[i] - mx); s2 += v[i]; }
    #pragma unroll
    for (int off = 32; off; off >>= 1) s2 += __shfl_down(s2, off, 64);
    __syncthreads();
    if (!lane) sb[4 + wid] = s2;
    __syncthreads();
    s2 = sb[4] + sb[5] + sb[6] + sb[7];
    float e = est[row];
    float sc = (1.f / (1.f + expf(-e))) / s2;
    __hip_bfloat16* pr = pb + row * S;
    #pragma unroll
    for (int i = 0; i < 4; ++i) {
        int c = threadIdx.x + i * 256;
        pr[c] = __float2bfloat16(v[i] * sc);
    }
}

extern "C" void kernel_launch(void* const* d_in, const int* in_sizes, int n_in,
                              void* d_out, int out_size, void* d_ws, size_t ws_size,
                              hipStream_t stream) {
    const int S = 1024, H = 32, HID = 4096, DH = 128, DL = 64;

    const float* hs   = (const float*)d_in[0];
    const float* mask = (const float*)d_in[1];
    const int*   pos  = (const int*)d_in[2];
    const float* Wq   = (const float*)d_in[3];
    const float* Wk   = (const float*)d_in[4];
    const float* Wv   = (const float*)d_in[5];
    const float* Wo   = (const float*)d_in[6];
    const float* Wdq  = (const float*)d_in[7];
    const float* Wdk  = (const float*)d_in[8];
    const float* ln1w = (const float*)d_in[9];
    const float* ln1b = (const float*)d_in[10];
    const float* ln2w = (const float*)d_in[11];
    const float* ln2b = (const float*)d_in[12];
    const float* cw   = (const float*)d_in[13];
    const float* cb   = (const float*)d_in[14];
    const float* sw   = (const float*)d_in[15];
    const float* sbia = (const float*)d_in[16];
    float* out = (float*)d_out;

    // ---- workspace: minimize loop-live fixed footprint ----
    float* p   = (float*)d_ws;
    float* ql  = p; p += (long)H * S * DL;
    float* kl  = p; p += (long)H * S * DL;
    float* est = p; p += (long)H * S;
    short* hsH = (short*)p; p += (long)S * HID / 2;   // later aoH (PV out bf16)
    short* hsL = (short*)p; p += (long)S * HID / 2;   // later vT bf16 [H][128][1024]
    float* region = p;                                 // everything else
    float* qb  = region;
    float* kb  = qb + (long)S * HID;
    short* WbH = (short*)(kb + (long)S * HID);
    short* WbL = WbH + (long)HID * HID;
    short* aoH = hsH;
    short* vT  = hsL;

    long wsFloats     = (long)(ws_size / 4);
    long regionFloats = wsFloats - (region - (float*)d_ws);
    long perHead      = 2L * S * S;                    // sc0 + sc1 fp32
    int CH = (int)(regionFloats / perHead);
    if (CH > H) CH = H;
    if (CH < 1) CH = 1;
    int iters = (H + CH - 1) / CH;
    CH = (H + iters - 1) / iters;                      // even chunks
    float* sc0 = region;
    float* sc1 = sc0 + (long)CH * S * S;
    __hip_bfloat16* pb = (__hip_bfloat16*)sc1;         // alias: sc1 dead after conv l2

    dim3 blk(256);
    long n4_hs = (long)S * HID / 4, n4_W = (long)HID * HID / 4;
    size_t projBytes = (size_t)S * HID * sizeof(float);

    // hs -> hi/lo bf16
    cvt_both<<<2048, blk, 0, stream>>>(hs, hsH, hsL, n4_hs);

    // ---- Q projection: 3 terms x 2 K-chunks (z=6, kSteps=64) — round-7 proven ----
    (void)hipMemsetAsync(qb, 0, projBytes, stream);
    cvt_both<<<2048, blk, 0, stream>>>(Wq, WbH, WbL, n4_W);
    gemm16_sk<<<dim3(HID / 128, S / 128, 6), blk, 0, stream>>>(
        (__hip_bfloat16*)hsH, (__hip_bfloat16*)hsL, (__hip_bfloat16*)hsH, HID,
        (__hip_bfloat16*)WbH, (__hip_bfloat16*)WbH, (__hip_bfloat16*)WbL, HID,
        qb, HID, 64, 2, 1.f);

    // ---- K projection ----
    (void)hipMemsetAsync(kb, 0, projBytes, stream);
    cvt_both<<<2048, blk, 0, stream>>>(Wk, WbH, WbL, n4_W);
    gemm16_sk<<<dim3(HID / 128, S / 128, 6), blk, 0, stream>>>(
        (__hip_bfloat16*)hsH, (__hip_bfloat16*)hsL, (__hip_bfloat16*)hsH, HID,
        (__hip_bfloat16*)WbH, (__hip_bfloat16*)WbH, (__hip_bfloat16*)WbL, HID,
        kb, HID, 64, 2, 1.f);

    // ---- V projection: hi-only, writes vT bf16 (overwrites hsL) ----
    cvt_part<false><<<2048, blk, 0, stream>>>(Wv, WbH, n4_W);
    gemm16<2><<<dim3(HID / 128, S / 128, 1), blk, 0, stream>>>(
        (__hip_bfloat16*)hsH, HID, 0, (__hip_bfloat16*)WbH, HID, 0, vT, S, 0, HID, 1.f);

    rope_kernel<<<(S * H * 64 + 255) / 256, blk, 0, stream>>>(qb, kb, pos);

    // low-rank down-proj (fp32 VALU, exact)
    gemm_f32<true><<<dim3(1, S / 64, H), blk, 0, stream>>>(qb, HID, 128, Wdq, DH, 0, ql, DL, (long)S * DL, S, DL, DH, 1.f);
    gemm_f32<true><<<dim3(1, S / 64, H), blk, 0, stream>>>(kb, HID, 128, Wdk, DH, 0, kl, DL, (long)S * DL, S, DL, DH, 1.f);
    // qb/kb/WbH/WbL now dead -> region becomes the score area

    for (int c0 = 0; c0 < H; c0 += CH) {
        int ch = (c0 + CH <= H) ? CH : (H - c0);
        gemm_s<<<dim3(S / 128, S / 128, ch), blk, 0, stream>>>(
            ql + (long)c0 * S * DL, DL, (long)S * DL,
            kl + (long)c0 * S * DL, DL, (long)S * DL,
            sc0, S, (long)S * S, DL, 0.125f);
        // est + LN1 in one pass (round-7 structure): sc0 -> sc1
        est_ln1<<<ch * S, blk, 0, stream>>>(sc0, sc1, sw, sbia, est + (long)c0 * S, ln1w, ln1b);
        conv_fast<<<dim3(16, 16, ch), blk, 0, stream>>>(sc1, sc0, cw, cb, 0, c0);
        conv_fast<<<dim3(16, 16, ch), blk, 0, stream>>>(sc0, sc1, cw, cb, 1, c0);
        conv_fast<<<dim3(16, 16, ch), blk, 0, stream>>>(sc1, sc0, cw, cb, 2, c0);
        // LN2 + mask + softmax + gate -> bf16 p (pb aliases sc1, dead now)
        ln2_softmax<<<ch * S, blk, 0, stream>>>(sc0, pb, ln2w, ln2b, mask, est + (long)c0 * S);
        // PV: 64x128 tiles, grid 16 x ch
        gemm_pv<<<dim3(S / 64, ch), blk, 0, stream>>>(
            pb, (long)S * S,
            (__hip_bfloat16*)(vT + (long)c0 * DH * S), (long)DH * S,
            (__hip_bfloat16*)(aoH + (long)c0 * 128), HID, 128);
    }

    // ---- final: out = aoH @ Wo^T (hi-only bf16, split-K atomic, z=2) ----
    short* WoH = (short*)region;   // scores dead after last PV
    cvt_part<false><<<2048, blk, 0, stream>>>(Wo, WoH, n4_W);
    (void)hipMemsetAsync(out, 0, projBytes, stream);
    gemm16_sk<<<dim3(HID / 128, S / 128, 2), blk, 0, stream>>>(
        (__hip_bfloat16*)aoH, (__hip_bfloat16*)aoH, (__hip_bfloat16*)aoH, HID,
        (__hip_bfloat16*)WoH, (__hip_bfloat16*)WoH, (__hip_bfloat16*)WoH, HID,
        out, HID, 64, 2, 1.f);
}

// Round 14
// 1018.244 us; speedup vs baseline: 1.3889x; 1.1084x over previous
//
#include <hip/hip_runtime.h>
#include <hip/hip_bf16.h>

typedef __attribute__((ext_vector_type(8))) short bf16x8;
typedef __attribute__((ext_vector_type(4))) float f32x4;

#define TILE 64
#define TK 16

__device__ inline short f2bf(float x) {
    unsigned u = __float_as_uint(x);
    unsigned r = (u + 0x7fffu + ((u >> 16) & 1u)) >> 16;
    return (short)r;
}
__device__ inline float bf2f(short h) {
    return __uint_as_float(((unsigned)(unsigned short)h) << 16);
}

// ---------------- fp32 VALU GEMM (down-proj only): C = A * B^T ----------------
template<bool BT>
__global__ __launch_bounds__(256)
void gemm_f32(const float* __restrict__ A, int lda, long sA,
              const float* __restrict__ B, int ldb, long sB,
              float* __restrict__ C, int ldc, long sC,
              int M, int N, int Kd, float alpha)
{
    long bz = blockIdx.z;
    A += bz * sA; B += bz * sB; C += bz * sC;
    int m0 = blockIdx.y * TILE, n0 = blockIdx.x * TILE;
    __shared__ float As[TK][TILE + 4];
    __shared__ float Bs[TK][TILE + 4];
    int tid = threadIdx.x;
    int tm = (tid >> 4) * 4;
    int tn = (tid & 15) * 4;
    float acc[4][4] = {};
    for (int k0 = 0; k0 < Kd; k0 += TK) {
        {
            int kk = tid & 15;
            int m  = tid >> 4;
            #pragma unroll
            for (int mm = 0; mm < 4; ++mm)
                As[kk][m + mm * 16] = A[(long)(m0 + m + mm * 16) * lda + k0 + kk];
        }
        {
            int kk = tid & 15;
            int n  = tid >> 4;
            #pragma unroll
            for (int nn = 0; nn < 4; ++nn)
                Bs[kk][n + nn * 16] = B[(long)(n0 + n + nn * 16) * ldb + k0 + kk];
        }
        __syncthreads();
        #pragma unroll
        for (int kk = 0; kk < TK; ++kk) {
            float4 a4 = *reinterpret_cast<const float4*>(&As[kk][tm]);
            float4 b4 = *reinterpret_cast<const float4*>(&Bs[kk][tn]);
            float a[4] = {a4.x, a4.y, a4.z, a4.w};
            float b[4] = {b4.x, b4.y, b4.z, b4.w};
            #pragma unroll
            for (int i = 0; i < 4; ++i)
                #pragma unroll
                for (int j = 0; j < 4; ++j)
                    acc[i][j] += a[i] * b[j];
        }
        __syncthreads();
    }
    #pragma unroll
    for (int i = 0; i < 4; ++i)
        #pragma unroll
        for (int j = 0; j < 4; ++j)
            C[(long)(m0 + tm + i) * ldc + n0 + tn + j] = alpha * acc[i][j];
}

// ---------------- m97-style bf16 MFMA GEMM: C (+)= alpha * A * B^T ----------------
// CMODE 0: C fp32 =, 1: C fp32 +=, 2: C^T bf16 (CT[n][m]), 3: C bf16 =
__device__ inline void gld_lds16(const __hip_bfloat16* g, __hip_bfloat16* l)
{
    __builtin_amdgcn_global_load_lds(
        (const __attribute__((address_space(1))) unsigned int*)g,
        (__attribute__((address_space(3))) unsigned int*)l,
        16, 0, 0);
}

template<int CMODE>
__global__ __launch_bounds__(256)
void gemm16(const __hip_bfloat16* __restrict__ A, int lda, long sA,
            const __hip_bfloat16* __restrict__ B, int ldb, long sB,
            void* __restrict__ Cv, int ldc, long sC,
            int Kd, float alpha)
{
    __shared__ __hip_bfloat16 As[128][32];
    __shared__ __hip_bfloat16 Bs[128][32];
    long bz = blockIdx.z;
    A += bz * sA; B += bz * sB;
    int m0 = blockIdx.y * 128, n0 = blockIdx.x * 128;
    int tid  = threadIdx.x;
    int w    = tid >> 6, lane = tid & 63;
    int wm   = w >> 1,  wn   = w & 1;
    int lrow = lane >> 2;
    int lseg = (lane & 3) * 8;
    int fr   = lane & 15;
    int kg   = (lane >> 4) * 8;
    f32x4 acc[4][4] = {};
    for (int k0 = 0; k0 < Kd; k0 += 32) {
        #pragma unroll
        for (int i = 0; i < 2; ++i) {
            int r = w * 32 + i * 16;
            gld_lds16(&A[(long)(m0 + r + lrow) * lda + k0 + lseg], &As[r][0]);
            gld_lds16(&B[(long)(n0 + r + lrow) * ldb + k0 + lseg], &Bs[r][0]);
        }
        __syncthreads();
        bf16x8 af[4], bfr[4];
        #pragma unroll
        for (int m = 0; m < 4; ++m)
            af[m] = *(const bf16x8*)&As[wm * 64 + m * 16 + fr][kg];
        #pragma unroll
        for (int n = 0; n < 4; ++n)
            bfr[n] = *(const bf16x8*)&Bs[wn * 64 + n * 16 + fr][kg];
        #pragma unroll
        for (int m = 0; m < 4; ++m)
            #pragma unroll
            for (int n = 0; n < 4; ++n)
                acc[m][n] = __builtin_amdgcn_mfma_f32_16x16x32_bf16(af[m], bfr[n], acc[m][n], 0, 0, 0);
        __syncthreads();
    }
    int crow0 = (lane >> 4) * 4;
    if constexpr (CMODE == 2) {
        __hip_bfloat16* CT = (__hip_bfloat16*)Cv + bz * sC;
        #pragma unroll
        for (int m = 0; m < 4; ++m)
            #pragma unroll
            for (int n = 0; n < 4; ++n)
                #pragma unroll
                for (int r = 0; r < 4; ++r) {
                    int row = m0 + wm * 64 + m * 16 + crow0 + r;
                    int col = n0 + wn * 64 + n * 16 + fr;
                    CT[(long)col * ldc + row] = __float2bfloat16(alpha * acc[m][n][r]);
                }
    } else if constexpr (CMODE == 3) {
        __hip_bfloat16* C = (__hip_bfloat16*)Cv + bz * sC;
        #pragma unroll
        for (int m = 0; m < 4; ++m)
            #pragma unroll
            for (int n = 0; n < 4; ++n)
                #pragma unroll
                for (int r = 0; r < 4; ++r)
                    C[(long)(m0 + wm * 64 + m * 16 + crow0 + r) * ldc
                      + n0 + wn * 64 + n * 16 + fr] = __float2bfloat16(alpha * acc[m][n][r]);
    } else {
        float* C = (float*)Cv + bz * sC;
        #pragma unroll
        for (int m = 0; m < 4; ++m)
            #pragma unroll
            for (int n = 0; n < 4; ++n)
                #pragma unroll
                for (int r = 0; r < 4; ++r) {
                    long idx = (long)(m0 + wm * 64 + m * 16 + crow0 + r) * ldc
                             + n0 + wn * 64 + n * 16 + fr;
                    float v = alpha * acc[m][n][r];
                    if constexpr (CMODE == 1) v += C[idx];
                    C[idx] = v;
                }
    }
}

// ---------------- single-pass 3-term split GEMM with K-split atomics ----------------
// C += AH*BH^T + AL*BH^T + AH*BL^T over this block's K-chunk; one atomicAdd per elem.
// All 4 tiles staged in LDS per K-step -> 48 MFMAs per barrier pair.
__global__ __launch_bounds__(256)
void gemm_3t(const __hip_bfloat16* __restrict__ AH, const __hip_bfloat16* __restrict__ AL, int lda,
             const __hip_bfloat16* __restrict__ BH, const __hip_bfloat16* __restrict__ BL, int ldb,
             float* __restrict__ C, int ldc, int kSteps)
{
    __shared__ __hip_bfloat16 Ahs[128][32];
    __shared__ __hip_bfloat16 Als[128][32];
    __shared__ __hip_bfloat16 Bhs[128][32];
    __shared__ __hip_bfloat16 Bls[128][32];
    int kbase = blockIdx.z * kSteps * 32;
    int m0 = blockIdx.y * 128, n0 = blockIdx.x * 128;
    int tid  = threadIdx.x;
    int w    = tid >> 6, lane = tid & 63;
    int wm   = w >> 1,  wn   = w & 1;
    int lrow = lane >> 2;
    int lseg = (lane & 3) * 8;
    int fr   = lane & 15;
    int kg   = (lane >> 4) * 8;
    f32x4 acc[4][4] = {};
    for (int it = 0; it < kSteps; ++it) {
        int k0 = kbase + it * 32;
        #pragma unroll
        for (int i = 0; i < 2; ++i) {
            int r = w * 32 + i * 16;
            long aoff = (long)(m0 + r + lrow) * lda + k0 + lseg;
            long boff = (long)(n0 + r + lrow) * ldb + k0 + lseg;
            gld_lds16(&AH[aoff], &Ahs[r][0]);
            gld_lds16(&AL[aoff], &Als[r][0]);
            gld_lds16(&BH[boff], &Bhs[r][0]);
            gld_lds16(&BL[boff], &Bls[r][0]);
        }
        __syncthreads();
        bf16x8 afh[4], afl[4], bfh[4], bfl[4];
        #pragma unroll
        for (int m = 0; m < 4; ++m) {
            afh[m] = *(const bf16x8*)&Ahs[wm * 64 + m * 16 + fr][kg];
            afl[m] = *(const bf16x8*)&Als[wm * 64 + m * 16 + fr][kg];
        }
        #pragma unroll
        for (int n = 0; n < 4; ++n) {
            bfh[n] = *(const bf16x8*)&Bhs[wn * 64 + n * 16 + fr][kg];
            bfl[n] = *(const bf16x8*)&Bls[wn * 64 + n * 16 + fr][kg];
        }
        #pragma unroll
        for (int m = 0; m < 4; ++m)
            #pragma unroll
            for (int n = 0; n < 4; ++n) {
                acc[m][n] = __builtin_amdgcn_mfma_f32_16x16x32_bf16(afh[m], bfh[n], acc[m][n], 0, 0, 0);
                acc[m][n] = __builtin_amdgcn_mfma_f32_16x16x32_bf16(afl[m], bfh[n], acc[m][n], 0, 0, 0);
                acc[m][n] = __builtin_amdgcn_mfma_f32_16x16x32_bf16(afh[m], bfl[n], acc[m][n], 0, 0, 0);
            }
        __syncthreads();
    }
    int crow0 = (lane >> 4) * 4;
    #pragma unroll
    for (int m = 0; m < 4; ++m)
        #pragma unroll
        for (int n = 0; n < 4; ++n)
            #pragma unroll
            for (int r = 0; r < 4; ++r) {
                long idx = (long)(m0 + wm * 64 + m * 16 + crow0 + r) * ldc
                         + n0 + wn * 64 + n * 16 + fr;
                atomicAdd(&C[idx], acc[m][n][r]);
            }
}

// ---------------- split-K/term bf16 MFMA GEMM with atomic accumulate (out proj) ----------------
__global__ __launch_bounds__(256)
void gemm16_sk(const __hip_bfloat16* __restrict__ A0, const __hip_bfloat16* __restrict__ A1,
               const __hip_bfloat16* __restrict__ A2, int lda,
               const __hip_bfloat16* __restrict__ B0, const __hip_bfloat16* __restrict__ B1,
               const __hip_bfloat16* __restrict__ B2, int ldb,
               float* __restrict__ C, int ldc,
               int kSteps, int chunksPerTerm, float alpha)
{
    __shared__ __hip_bfloat16 As[128][32];
    __shared__ __hip_bfloat16 Bs[128][32];
    int z    = blockIdx.z;
    int term = z / chunksPerTerm;
    int sub  = z - term * chunksPerTerm;
    const __hip_bfloat16* A = (term == 0) ? A0 : (term == 1) ? A1 : A2;
    const __hip_bfloat16* B = (term == 0) ? B0 : (term == 1) ? B1 : B2;
    int kbase = sub * kSteps * 32;
    int m0 = blockIdx.y * 128, n0 = blockIdx.x * 128;
    int tid  = threadIdx.x;
    int w    = tid >> 6, lane = tid & 63;
    int wm   = w >> 1,  wn   = w & 1;
    int lrow = lane >> 2;
    int lseg = (lane & 3) * 8;
    int fr   = lane & 15;
    int kg   = (lane >> 4) * 8;
    f32x4 acc[4][4] = {};
    for (int it = 0; it < kSteps; ++it) {
        int k0 = kbase + it * 32;
        #pragma unroll
        for (int i = 0; i < 2; ++i) {
            int r = w * 32 + i * 16;
            gld_lds16(&A[(long)(m0 + r + lrow) * lda + k0 + lseg], &As[r][0]);
            gld_lds16(&B[(long)(n0 + r + lrow) * ldb + k0 + lseg], &Bs[r][0]);
        }
        __syncthreads();
        bf16x8 af[4], bfr[4];
        #pragma unroll
        for (int m = 0; m < 4; ++m)
            af[m] = *(const bf16x8*)&As[wm * 64 + m * 16 + fr][kg];
        #pragma unroll
        for (int n = 0; n < 4; ++n)
            bfr[n] = *(const bf16x8*)&Bs[wn * 64 + n * 16 + fr][kg];
        #pragma unroll
        for (int m = 0; m < 4; ++m)
            #pragma unroll
            for (int n = 0; n < 4; ++n)
                acc[m][n] = __builtin_amdgcn_mfma_f32_16x16x32_bf16(af[m], bfr[n], acc[m][n], 0, 0, 0);
        __syncthreads();
    }
    int crow0 = (lane >> 4) * 4;
    #pragma unroll
    for (int m = 0; m < 4; ++m)
        #pragma unroll
        for (int n = 0; n < 4; ++n)
            #pragma unroll
            for (int r = 0; r < 4; ++r) {
                long idx = (long)(m0 + wm * 64 + m * 16 + crow0 + r) * ldc
                         + n0 + wn * 64 + n * 16 + fr;
                atomicAdd(&C[idx], alpha * acc[m][n][r]);
            }
}

// ---------------- PV GEMM, 64x128 tile: aoH bf16 = pb * vT^T ----------------
__global__ __launch_bounds__(256)
void gemm_pv(const __hip_bfloat16* __restrict__ Ab, long sA,
             const __hip_bfloat16* __restrict__ Bb, long sB,
             __hip_bfloat16* __restrict__ C, int ldc, long sC)
{
    __shared__ __hip_bfloat16 As[64][32];
    __shared__ __hip_bfloat16 Bs[128][32];
    const int S = 1024;
    int h  = blockIdx.y;
    const __hip_bfloat16* A = Ab + (long)h * sA;
    const __hip_bfloat16* B = Bb + (long)h * sB;
    __hip_bfloat16* Ch = C + (long)h * sC;
    int m0 = blockIdx.x * 64;
    int tid  = threadIdx.x;
    int w    = tid >> 6, lane = tid & 63;
    int wm   = w >> 1,  wn   = w & 1;
    int lrow = lane >> 2;
    int lseg = (lane & 3) * 8;
    int fr   = lane & 15;
    int kg   = (lane >> 4) * 8;
    f32x4 acc[2][4] = {};
    for (int k0 = 0; k0 < S; k0 += 32) {
        gld_lds16(&A[(long)(m0 + w * 16 + lrow) * S + k0 + lseg], &As[w * 16][0]);
        #pragma unroll
        for (int i = 0; i < 2; ++i) {
            int r = w * 32 + i * 16;
            gld_lds16(&B[(long)(r + lrow) * S + k0 + lseg], &Bs[r][0]);
        }
        __syncthreads();
        bf16x8 af[2], bfr[4];
        #pragma unroll
        for (int m = 0; m < 2; ++m)
            af[m] = *(const bf16x8*)&As[wm * 32 + m * 16 + fr][kg];
        #pragma unroll
        for (int n = 0; n < 4; ++n)
            bfr[n] = *(const bf16x8*)&Bs[wn * 64 + n * 16 + fr][kg];
        #pragma unroll
        for (int m = 0; m < 2; ++m)
            #pragma unroll
            for (int n = 0; n < 4; ++n)
                acc[m][n] = __builtin_amdgcn_mfma_f32_16x16x32_bf16(af[m], bfr[n], acc[m][n], 0, 0, 0);
        __syncthreads();
    }
    int crow0 = (lane >> 4) * 4;
    #pragma unroll
    for (int m = 0; m < 2; ++m)
        #pragma unroll
        for (int n = 0; n < 4; ++n)
            #pragma unroll
            for (int r = 0; r < 4; ++r)
                Ch[(long)(m0 + wm * 32 + m * 16 + crow0 + r) * ldc
                   + wn * 64 + n * 16 + fr] = __float2bfloat16(acc[m][n][r]);
}

// ---------------- in-register split MFMA GEMM (QK^T): C = alpha * A * B^T ----------------
#define LP 40
__global__ __launch_bounds__(256)
void gemm_s(const float* __restrict__ A, int lda, long sA,
            const float* __restrict__ B, int ldb, long sB,
            float* __restrict__ C, int ldc, long sC,
            int Kd, float alpha)
{
    __shared__ short Ah[128][LP];
    __shared__ short Bh[128][LP];
    __shared__ short Al[128][LP];
    __shared__ short Bl[128][LP];
    long bz = blockIdx.z;
    A += bz * sA; B += bz * sB; C += bz * sC;
    int m0 = blockIdx.y * 128, n0 = blockIdx.x * 128;
    int tid  = threadIdx.x;
    int lane = tid & 63;
    int w    = tid >> 6;
    int wm   = w >> 1, wn = w & 1;
    int srow = tid >> 1;
    int scol = (tid & 1) * 16;
    int fr   = lane & 15;
    int kg   = (lane >> 4) * 8;
    f32x4 acc[4][4] = {};
    for (int k0 = 0; k0 < Kd; k0 += 32) {
        #pragma unroll
        for (int ab = 0; ab < 2; ++ab) {
            const float* src = ab ? (B + (long)(n0 + srow) * ldb + k0 + scol)
                                  : (A + (long)(m0 + srow) * lda + k0 + scol);
            short* dh = ab ? &Bh[srow][scol] : &Ah[srow][scol];
            short* dl = ab ? &Bl[srow][scol] : &Al[srow][scol];
            #pragma unroll
            for (int half = 0; half < 2; ++half) {
                float4 x0 = *reinterpret_cast<const float4*>(src + half * 8);
                float4 x1 = *reinterpret_cast<const float4*>(src + half * 8 + 4);
                float xs[8] = {x0.x, x0.y, x0.z, x0.w, x1.x, x1.y, x1.z, x1.w};
                bf16x8 hv, lv;
                #pragma unroll
                for (int j = 0; j < 8; ++j) {
                    short hb = f2bf(xs[j]);
                    hv[j] = hb;
                    lv[j] = f2bf(xs[j] - bf2f(hb));
                }
                *reinterpret_cast<bf16x8*>(dh + half * 8) = hv;
                *reinterpret_cast<bf16x8*>(dl + half * 8) = lv;
            }
        }
        __syncthreads();
        bf16x8 afh[4], bfh[4], afl[4], bfl[4];
        #pragma unroll
        for (int m = 0; m < 4; ++m) {
            afh[m] = *(const bf16x8*)&Ah[wm * 64 + m * 16 + fr][kg];
            afl[m] = *(const bf16x8*)&Al[wm * 64 + m * 16 + fr][kg];
        }
        #pragma unroll
        for (int n = 0; n < 4; ++n) {
            bfh[n] = *(const bf16x8*)&Bh[wn * 64 + n * 16 + fr][kg];
            bfl[n] = *(const bf16x8*)&Bl[wn * 64 + n * 16 + fr][kg];
        }
        #pragma unroll
        for (int m = 0; m < 4; ++m)
            #pragma unroll
            for (int n = 0; n < 4; ++n) {
                acc[m][n] = __builtin_amdgcn_mfma_f32_16x16x32_bf16(afh[m], bfh[n], acc[m][n], 0, 0, 0);
                acc[m][n] = __builtin_amdgcn_mfma_f32_16x16x32_bf16(afh[m], bfl[n], acc[m][n], 0, 0, 0);
                acc[m][n] = __builtin_amdgcn_mfma_f32_16x16x32_bf16(afl[m], bfh[n], acc[m][n], 0, 0, 0);
            }
        __syncthreads();
    }
    int crow0 = (lane >> 4) * 4;
    #pragma unroll
    for (int m = 0; m < 4; ++m)
        #pragma unroll
        for (int n = 0; n < 4; ++n)
            #pragma unroll
            for (int r = 0; r < 4; ++r)
                C[(long)(m0 + wm * 64 + m * 16 + crow0 + r) * ldc
                  + n0 + wn * 64 + n * 16 + fr] = alpha * acc[m][n][r];
}

// ---------------- f32 -> bf16 hi or lo part (n4 = n/4) ----------------
struct alignas(8) s4 { short a, b, c, d; };
template<bool LO>
__global__ __launch_bounds__(256)
void cvt_part(const float* __restrict__ x, short* __restrict__ y, long n4)
{
    long i = (long)blockIdx.x * 256 + threadIdx.x;
    long stride = (long)gridDim.x * 256;
    for (; i < n4; i += stride) {
        float4 v = reinterpret_cast<const float4*>(x)[i];
        float xs[4] = {v.x, v.y, v.z, v.w};
        s4 o;
        short* op = &o.a;
        #pragma unroll
        for (int j = 0; j < 4; ++j) {
            short hb = f2bf(xs[j]);
            op[j] = LO ? f2bf(xs[j] - bf2f(hb)) : hb;
        }
        reinterpret_cast<s4*>(y)[i] = o;
    }
}

// ---------------- f32 -> bf16 hi AND lo in one pass ----------------
__global__ __launch_bounds__(256)
void cvt_both(const float* __restrict__ x, short* __restrict__ yh,
              short* __restrict__ yl, long n4)
{
    long i = (long)blockIdx.x * 256 + threadIdx.x;
    long stride = (long)gridDim.x * 256;
    for (; i < n4; i += stride) {
        float4 v = reinterpret_cast<const float4*>(x)[i];
        float xs[4] = {v.x, v.y, v.z, v.w};
        s4 oh, ol;
        short* hp = &oh.a; short* lp = &ol.a;
        #pragma unroll
        for (int j = 0; j < 4; ++j) {
            short hb = f2bf(xs[j]);
            hp[j] = hb;
            lp[j] = f2bf(xs[j] - bf2f(hb));
        }
        reinterpret_cast<s4*>(yh)[i] = oh;
        reinterpret_cast<s4*>(yl)[i] = ol;
    }
}

// ---------------- RoPE in place on q,k [S][4096] ----------------
__global__ __launch_bounds__(256)
void rope_kernel(float* __restrict__ q, float* __restrict__ k, const int* __restrict__ pos)
{
    int i = blockIdx.x * 256 + threadIdx.x;
    if (i >= 1024 * 32 * 64) return;
    int d   = i & 63;
    int rem = i >> 6;
    int h   = rem & 31;
    int s   = rem >> 5;
    float p = (float)pos[s];
    float inv = exp2f(-(float)d * (13.287712379549449f / 64.0f));
    float ang = p * inv;
    float c = cosf(ang), sn = sinf(ang);
    long base = ((long)s * 4096) + h * 128 + d;
    float x1 = q[base], x2 = q[base + 64];
    q[base]      = x1 * c - x2 * sn;
    q[base + 64] = x2 * c + x1 * sn;
    x1 = k[base]; x2 = k[base + 64];
    k[base]      = x1 * c - x2 * sn;
    k[base + 64] = x2 * c + x1 * sn;
}

// ---------------- fused est + LayerNorm1: sc0 -> sc1, est ----------------
__global__ __launch_bounds__(256)
void est_ln1(const float* __restrict__ x, float* __restrict__ y,
             const float* __restrict__ sw, const float* __restrict__ sbias,
             float* __restrict__ est,
             const float* __restrict__ w, const float* __restrict__ b)
{
    long row = blockIdx.x;
    const float* xr = x + row * 1024;
    float* yr = y + row * 1024;
    __shared__ float sb[12];
    float v[4];
    float s = 0.f, ss = 0.f, dt = 0.f;
    #pragma unroll
    for (int i = 0; i < 4; ++i) {
        int c = threadIdx.x + i * 256;
        v[i] = xr[c];
        s += v[i]; ss += v[i] * v[i]; dt += v[i] * sw[c];
    }
    #pragma unroll
    for (int off = 32; off; off >>= 1) {
        s  += __shfl_down(s, off, 64);
        ss += __shfl_down(ss, off, 64);
        dt += __shfl_down(dt, off, 64);
    }
    int wid = threadIdx.x >> 6, lane = threadIdx.x & 63;
    if (!lane) { sb[wid] = s; sb[4 + wid] = ss; sb[8 + wid] = dt; }
    __syncthreads();
    s  = sb[0] + sb[1] + sb[2] + sb[3];
    ss = sb[4] + sb[5] + sb[6] + sb[7];
    if (threadIdx.x == 0) est[row] = sb[8] + sb[9] + sb[10] + sb[11] + sbias[0];
    float mean = s * (1.f / 1024.f);
    float var  = ss * (1.f / 1024.f) - mean * mean;
    float inv  = rsqrtf(var + 1e-5f);
    #pragma unroll
    for (int i = 0; i < 4; ++i) {
        int c = threadIdx.x + i * 256;
        yr[c] = (v[i] - mean) * inv * w[c] + b[c];
    }
}

// ---------------- causal depthwise conv + ReLU, register-tap ----------------
__global__ __launch_bounds__(256)
void conv_fast(const float* __restrict__ x, float* __restrict__ y,
               const float* __restrict__ cw, const float* __restrict__ cb,
               int layer, int h0)
{
    const int S = 1024;
    int h  = blockIdx.z;
    int hg = h0 + h;
    int q0 = blockIdx.y * 64;
    int k0 = blockIdx.x * 64;
    __shared__ float ws[63];
    if (threadIdx.x < 63) ws[threadIdx.x] = cw[(layer * 32 + hg) * 63 + threadIdx.x];
    __syncthreads();
    int c   = threadIdx.x & 63;
    int grp = threadIdx.x >> 6;
    int qb  = q0 + grp * 16;
    const float* xh = x + (long)h * S * S + k0 + c;
    float X[78];
    #pragma unroll
    for (int j = 0; j < 78; ++j) {
        int g = qb - 62 + j;
        X[j] = (g >= 0) ? xh[(long)g * S] : 0.f;
    }
    float wr[63];
    #pragma unroll
    for (int t = 0; t < 63; ++t) wr[t] = ws[t];
    float bias = cb[layer * 32 + hg];
    float* yh = y + (long)h * S * S + k0 + c;
    #pragma unroll
    for (int i = 0; i < 16; ++i) {
        float a0 = 0.f, a1 = 0.f, a2 = 0.f, a3 = 0.f;
        #pragma unroll
        for (int t = 0; t < 60; t += 4) {
            a0 += wr[t]     * X[i + t];
            a1 += wr[t + 1] * X[i + t + 1];
            a2 += wr[t + 2] * X[i + t + 2];
            a3 += wr[t + 3] * X[i + t + 3];
        }
        a0 += wr[60] * X[i + 60];
        a1 += wr[61] * X[i + 61];
        a2 += wr[62] * X[i + 62];
        float acc = bias + ((a0 + a1) + (a2 + a3));
        yh[(long)(qb + i) * S] = fmaxf(acc, 0.f);
    }
}

// ---------------- fused LayerNorm2 + mask + softmax + sigmoid gate -> bf16 p ----------------
__global__ __launch_bounds__(256)
void ln2_softmax(const float* __restrict__ x, __hip_bfloat16* __restrict__ pb,
                 const float* __restrict__ w, const float* __restrict__ b,
                 const float* __restrict__ mask, const float* __restrict__ est)
{
    const int S = 1024;
    long row = blockIdx.x;
    int q = (int)(row & (S - 1));
    const float* xr = x + row * 1024;
    const float* mrow = mask + (long)q * S;
    __shared__ float sb[8];
    float v[4];
    float s = 0.f, ss = 0.f;
    #pragma unroll
    for (int i = 0; i < 4; ++i) {
        int c = threadIdx.x + i * 256;
        v[i] = xr[c];
        s += v[i]; ss += v[i] * v[i];
    }
    #pragma unroll
    for (int off = 32; off; off >>= 1) {
        s  += __shfl_down(s, off, 64);
        ss += __shfl_down(ss, off, 64);
    }
    int wid = threadIdx.x >> 6, lane = threadIdx.x & 63;
    if (!lane) { sb[wid] = s; sb[4 + wid] = ss; }
    __syncthreads();
    s  = sb[0] + sb[1] + sb[2] + sb[3];
    ss = sb[4] + sb[5] + sb[6] + sb[7];
    float mean = s * (1.f / 1024.f);
    float var  = ss * (1.f / 1024.f) - mean * mean;
    float inv  = rsqrtf(var + 1e-5f);
    const float FMIN = -3.4028235e38f;
    float mx = FMIN;
    #pragma unroll
    for (int i = 0; i < 4; ++i) {
        int c = threadIdx.x + i * 256;
        float t = (v[i] - mean) * inv * w[c] + b[c] + mrow[c];
        t = fmaxf(t, FMIN);
        v[i] = t;
        mx = fmaxf(mx, t);
    }
    #pragma unroll
    for (int off = 32; off; off >>= 1) mx = fmaxf(mx, __shfl_down(mx, off, 64));
    __syncthreads();
    if (!lane) sb[wid] = mx;
    __syncthreads();
    mx = fmaxf(fmaxf(sb[0], sb[1]), fmaxf(sb[2], sb[3]));
    float s2 = 0.f;
    #pragma unroll
    for (int i = 0; i < 4; ++i) { v[i] = expf(v[i] - mx); s2 += v[i]; }
    #pragma unroll
    for (int off = 32; off; off >>= 1) s2 += __shfl_down(s2, off, 64);
    __syncthreads();
    if (!lane) sb[4 + wid] = s2;
    __syncthreads();
    s2 = sb[4] + sb[5] + sb[6] + sb[7];
    float e = est[row];
    float sc = (1.f / (1.f + expf(-e))) / s2;
    __hip_bfloat16* pr = pb + row * S;
    #pragma unroll
    for (int i = 0; i < 4; ++i) {
        int c = threadIdx.x + i * 256;
        pr[c] = __float2bfloat16(v[i] * sc);
    }
}

extern "C" void kernel_launch(void* const* d_in, const int* in_sizes, int n_in,
                              void* d_out, int out_size, void* d_ws, size_t ws_size,
                              hipStream_t stream) {
    const int S = 1024, H = 32, HID = 4096, DH = 128, DL = 64;

    const float* hs   = (const float*)d_in[0];
    const float* mask = (const float*)d_in[1];
    const int*   pos  = (const int*)d_in[2];
    const float* Wq   = (const float*)d_in[3];
    const float* Wk   = (const float*)d_in[4];
    const float* Wv   = (const float*)d_in[5];
    const float* Wo   = (const float*)d_in[6];
    const float* Wdq  = (const float*)d_in[7];
    const float* Wdk  = (const float*)d_in[8];
    const float* ln1w = (const float*)d_in[9];
    const float* ln1b = (const float*)d_in[10];
    const float* ln2w = (const float*)d_in[11];
    const float* ln2b = (const float*)d_in[12];
    const float* cw   = (const float*)d_in[13];
    const float* cb   = (const float*)d_in[14];
    const float* sw   = (const float*)d_in[15];
    const float* sbia = (const float*)d_in[16];
    float* out = (float*)d_out;

    // ---- workspace: minimize loop-live fixed footprint ----
    float* p   = (float*)d_ws;
    float* ql  = p; p += (long)H * S * DL;
    float* kl  = p; p += (long)H * S * DL;
    float* est = p; p += (long)H * S;
    short* hsH = (short*)p; p += (long)S * HID / 2;   // later aoH (PV out bf16)
    short* hsL = (short*)p; p += (long)S * HID / 2;   // later vT bf16 [H][128][1024]
    float* region = p;                                 // everything else
    float* qb  = region;
    float* kb  = qb + (long)S * HID;
    short* WbH = (short*)(kb + (long)S * HID);
    short* WbL = WbH + (long)HID * HID;
    short* aoH = hsH;
    short* vT  = hsL;

    long wsFloats     = (long)(ws_size / 4);
    long regionFloats = wsFloats - (region - (float*)d_ws);
    long perHead      = 2L * S * S;                    // sc0 + sc1 fp32
    int CH = (int)(regionFloats / perHead);
    if (CH > H) CH = H;
    if (CH < 1) CH = 1;
    int iters = (H + CH - 1) / CH;
    CH = (H + iters - 1) / iters;                      // even chunks
    float* sc0 = region;
    float* sc1 = sc0 + (long)CH * S * S;
    __hip_bfloat16* pb = (__hip_bfloat16*)sc1;         // alias: sc1 dead after conv l2

    dim3 blk(256);
    long n4_hs = (long)S * HID / 4, n4_W = (long)HID * HID / 4;
    size_t projBytes = (size_t)S * HID * sizeof(float);

    // hs -> hi/lo bf16
    cvt_both<<<2048, blk, 0, stream>>>(hs, hsH, hsL, n4_hs);

    // ---- Q projection: single-pass 3-term, z=2 K-split (32MB atomics) ----
    (void)hipMemsetAsync(qb, 0, projBytes, stream);
    cvt_both<<<2048, blk, 0, stream>>>(Wq, WbH, WbL, n4_W);
    gemm_3t<<<dim3(HID / 128, S / 128, 2), blk, 0, stream>>>(
        (__hip_bfloat16*)hsH, (__hip_bfloat16*)hsL, HID,
        (__hip_bfloat16*)WbH, (__hip_bfloat16*)WbL, HID,
        qb, HID, 64);

    // ---- K projection ----
    (void)hipMemsetAsync(kb, 0, projBytes, stream);
    cvt_both<<<2048, blk, 0, stream>>>(Wk, WbH, WbL, n4_W);
    gemm_3t<<<dim3(HID / 128, S / 128, 2), blk, 0, stream>>>(
        (__hip_bfloat16*)hsH, (__hip_bfloat16*)hsL, HID,
        (__hip_bfloat16*)WbH, (__hip_bfloat16*)WbL, HID,
        kb, HID, 64);

    // ---- V projection: hi-only, writes vT bf16 (overwrites hsL) ----
    cvt_part<false><<<2048, blk, 0, stream>>>(Wv, WbH, n4_W);
    gemm16<2><<<dim3(HID / 128, S / 128, 1), blk, 0, stream>>>(
        (__hip_bfloat16*)hsH, HID, 0, (__hip_bfloat16*)WbH, HID, 0, vT, S, 0, HID, 1.f);

    rope_kernel<<<(S * H * 64 + 255) / 256, blk, 0, stream>>>(qb, kb, pos);

    // low-rank down-proj (fp32 VALU, exact)
    gemm_f32<true><<<dim3(1, S / 64, H), blk, 0, stream>>>(qb, HID, 128, Wdq, DH, 0, ql, DL, (long)S * DL, S, DL, DH, 1.f);
    gemm_f32<true><<<dim3(1, S / 64, H), blk, 0, stream>>>(kb, HID, 128, Wdk, DH, 0, kl, DL, (long)S * DL, S, DL, DH, 1.f);
    // qb/kb/WbH/WbL now dead -> region becomes the score area

    for (int c0 = 0; c0 < H; c0 += CH) {
        int ch = (c0 + CH <= H) ? CH : (H - c0);
        gemm_s<<<dim3(S / 128, S / 128, ch), blk, 0, stream>>>(
            ql + (long)c0 * S * DL, DL, (long)S * DL,
            kl + (long)c0 * S * DL, DL, (long)S * DL,
            sc0, S, (long)S * S, DL, 0.125f);
        est_ln1<<<ch * S, blk, 0, stream>>>(sc0, sc1, sw, sbia, est + (long)c0 * S, ln1w, ln1b);
        conv_fast<<<dim3(16, 16, ch), blk, 0, stream>>>(sc1, sc0, cw, cb, 0, c0);
        conv_fast<<<dim3(16, 16, ch), blk, 0, stream>>>(sc0, sc1, cw, cb, 1, c0);
        conv_fast<<<dim3(16, 16, ch), blk, 0, stream>>>(sc1, sc0, cw, cb, 2, c0);
        ln2_softmax<<<ch * S, blk, 0, stream>>>(sc0, pb, ln2w, ln2b, mask, est + (long)c0 * S);
        gemm_pv<<<dim3(S / 64, ch), blk, 0, stream>>>(
            pb, (long)S * S,
            (__hip_bfloat16*)(vT + (long)c0 * DH * S), (long)DH * S,
            (__hip_bfloat16*)(aoH + (long)c0 * 128), HID, 128);
    }

    // ---- final: out = aoH @ Wo^T (hi-only bf16, split-K atomic, z=2) ----
    short* WoH = (short*)region;   // scores dead after last PV
    cvt_part<false><<<2048, blk, 0, stream>>>(Wo, WoH, n4_W);
    (void)hipMemsetAsync(out, 0, projBytes, stream);
    gemm16_sk<<<dim3(HID / 128, S / 128, 2), blk, 0, stream>>>(
        (__hip_bfloat16*)aoH, (__hip_bfloat16*)aoH, (__hip_bfloat16*)aoH, HID,
        (__hip_bfloat16*)WoH, (__hip_bfloat16*)WoH, (__hip_bfloat16*)WoH, HID,
        out, HID, 64, 2, 1.f);
}

// Round 15
// 977.070 us; speedup vs baseline: 1.4474x; 1.0421x over previous
//
#include <hip/hip_runtime.h>
#include <hip/hip_bf16.h>

typedef __attribute__((ext_vector_type(8))) short bf16x8;
typedef __attribute__((ext_vector_type(4))) float f32x4;

#define TILE 64
#define TK 16

__device__ inline short f2bf(float x) {
    unsigned u = __float_as_uint(x);
    unsigned r = (u + 0x7fffu + ((u >> 16) & 1u)) >> 16;
    return (short)r;
}
__device__ inline float bf2f(short h) {
    return __uint_as_float(((unsigned)(unsigned short)h) << 16);
}

// ---------------- fp32 VALU GEMM (down-proj only): C = A * B^T ----------------
template<bool BT>
__global__ __launch_bounds__(256)
void gemm_f32(const float* __restrict__ A, int lda, long sA,
              const float* __restrict__ B, int ldb, long sB,
              float* __restrict__ C, int ldc, long sC,
              int M, int N, int Kd, float alpha)
{
    long bz = blockIdx.z;
    A += bz * sA; B += bz * sB; C += bz * sC;
    int m0 = blockIdx.y * TILE, n0 = blockIdx.x * TILE;
    __shared__ float As[TK][TILE + 4];
    __shared__ float Bs[TK][TILE + 4];
    int tid = threadIdx.x;
    int tm = (tid >> 4) * 4;
    int tn = (tid & 15) * 4;
    float acc[4][4] = {};
    for (int k0 = 0; k0 < Kd; k0 += TK) {
        {
            int kk = tid & 15;
            int m  = tid >> 4;
            #pragma unroll
            for (int mm = 0; mm < 4; ++mm)
                As[kk][m + mm * 16] = A[(long)(m0 + m + mm * 16) * lda + k0 + kk];
        }
        {
            int kk = tid & 15;
            int n  = tid >> 4;
            #pragma unroll
            for (int nn = 0; nn < 4; ++nn)
                Bs[kk][n + nn * 16] = B[(long)(n0 + n + nn * 16) * ldb + k0 + kk];
        }
        __syncthreads();
        #pragma unroll
        for (int kk = 0; kk < TK; ++kk) {
            float4 a4 = *reinterpret_cast<const float4*>(&As[kk][tm]);
            float4 b4 = *reinterpret_cast<const float4*>(&Bs[kk][tn]);
            float a[4] = {a4.x, a4.y, a4.z, a4.w};
            float b[4] = {b4.x, b4.y, b4.z, b4.w};
            #pragma unroll
            for (int i = 0; i < 4; ++i)
                #pragma unroll
                for (int j = 0; j < 4; ++j)
                    acc[i][j] += a[i] * b[j];
        }
        __syncthreads();
    }
    #pragma unroll
    for (int i = 0; i < 4; ++i)
        #pragma unroll
        for (int j = 0; j < 4; ++j)
            C[(long)(m0 + tm + i) * ldc + n0 + tn + j] = alpha * acc[i][j];
}

__device__ inline void gld_lds16(const __hip_bfloat16* g, __hip_bfloat16* l)
{
    __builtin_amdgcn_global_load_lds(
        (const __attribute__((address_space(1))) unsigned int*)g,
        (__attribute__((address_space(3))) unsigned int*)l,
        16, 0, 0);
}

// ---------------- 64x128-tile MFMA GEMM, full K per block, no atomics ----------------
// C = alpha * (AH*BH^T [+ AL*BH^T + AH*BL^T if SPLIT3]); A MxK, B NxK bf16 row-major.
// grid = (N/128, M/64). CMODE 0: C fp32 =; 2: C^T bf16 (CT[n][m], ldc=row len of CT);
// 3: C bf16 =.
template<int CMODE, bool SPLIT3>
__global__ __launch_bounds__(256)
void gemm64(const __hip_bfloat16* __restrict__ AH, const __hip_bfloat16* __restrict__ AL, int lda,
            const __hip_bfloat16* __restrict__ BH, const __hip_bfloat16* __restrict__ BL, int ldb,
            void* __restrict__ Cv, int ldc, int Kd, float alpha)
{
    __shared__ __hip_bfloat16 Ahs[64][32];
    __shared__ __hip_bfloat16 Als[SPLIT3 ? 64 : 1][32];
    __shared__ __hip_bfloat16 Bhs[128][32];
    __shared__ __hip_bfloat16 Bls[SPLIT3 ? 128 : 1][32];
    int m0 = blockIdx.y * 64, n0 = blockIdx.x * 128;
    int tid  = threadIdx.x;
    int w    = tid >> 6, lane = tid & 63;
    int wm   = w >> 1,  wn   = w & 1;
    int lrow = lane >> 2;
    int lseg = (lane & 3) * 8;
    int fr   = lane & 15;
    int kg   = (lane >> 4) * 8;
    f32x4 acc[2][4] = {};
    for (int k0 = 0; k0 < Kd; k0 += 32) {
        // A: wave w stages rows w*16 .. w*16+15
        {
            long aoff = (long)(m0 + w * 16 + lrow) * lda + k0 + lseg;
            gld_lds16(&AH[aoff], &Ahs[w * 16][0]);
            if (SPLIT3) gld_lds16(&AL[aoff], &Als[w * 16][0]);
        }
        // B: wave w stages rows w*32 .. w*32+31 (two 16-row chunks)
        #pragma unroll
        for (int i = 0; i < 2; ++i) {
            int r = w * 32 + i * 16;
            long boff = (long)(n0 + r + lrow) * ldb + k0 + lseg;
            gld_lds16(&BH[boff], &Bhs[r][0]);
            if (SPLIT3) gld_lds16(&BL[boff], &Bls[r][0]);
        }
        __syncthreads();
        bf16x8 afh[2], afl[2], bfh[4], bfl[4];
        #pragma unroll
        for (int m = 0; m < 2; ++m) {
            afh[m] = *(const bf16x8*)&Ahs[wm * 32 + m * 16 + fr][kg];
            if (SPLIT3) afl[m] = *(const bf16x8*)&Als[wm * 32 + m * 16 + fr][kg];
        }
        #pragma unroll
        for (int n = 0; n < 4; ++n) {
            bfh[n] = *(const bf16x8*)&Bhs[wn * 64 + n * 16 + fr][kg];
            if (SPLIT3) bfl[n] = *(const bf16x8*)&Bls[wn * 64 + n * 16 + fr][kg];
        }
        #pragma unroll
        for (int m = 0; m < 2; ++m)
            #pragma unroll
            for (int n = 0; n < 4; ++n) {
                acc[m][n] = __builtin_amdgcn_mfma_f32_16x16x32_bf16(afh[m], bfh[n], acc[m][n], 0, 0, 0);
                if (SPLIT3) {
                    acc[m][n] = __builtin_amdgcn_mfma_f32_16x16x32_bf16(afl[m], bfh[n], acc[m][n], 0, 0, 0);
                    acc[m][n] = __builtin_amdgcn_mfma_f32_16x16x32_bf16(afh[m], bfl[n], acc[m][n], 0, 0, 0);
                }
            }
        __syncthreads();
    }
    int crow0 = (lane >> 4) * 4;
    if constexpr (CMODE == 2) {
        __hip_bfloat16* CT = (__hip_bfloat16*)Cv;
        #pragma unroll
        for (int m = 0; m < 2; ++m)
            #pragma unroll
            for (int n = 0; n < 4; ++n)
                #pragma unroll
                for (int r = 0; r < 4; ++r) {
                    int row = m0 + wm * 32 + m * 16 + crow0 + r;
                    int col = n0 + wn * 64 + n * 16 + fr;
                    CT[(long)col * ldc + row] = __float2bfloat16(alpha * acc[m][n][r]);
                }
    } else if constexpr (CMODE == 3) {
        __hip_bfloat16* C = (__hip_bfloat16*)Cv;
        #pragma unroll
        for (int m = 0; m < 2; ++m)
            #pragma unroll
            for (int n = 0; n < 4; ++n)
                #pragma unroll
                for (int r = 0; r < 4; ++r)
                    C[(long)(m0 + wm * 32 + m * 16 + crow0 + r) * ldc
                      + n0 + wn * 64 + n * 16 + fr] = __float2bfloat16(alpha * acc[m][n][r]);
    } else {
        float* C = (float*)Cv;
        #pragma unroll
        for (int m = 0; m < 2; ++m)
            #pragma unroll
            for (int n = 0; n < 4; ++n)
                #pragma unroll
                for (int r = 0; r < 4; ++r)
                    C[(long)(m0 + wm * 32 + m * 16 + crow0 + r) * ldc
                      + n0 + wn * 64 + n * 16 + fr] = alpha * acc[m][n][r];
    }
}

// ---------------- PV GEMM, 64x128 tile: aoH bf16 = pb * vT^T ----------------
__global__ __launch_bounds__(256)
void gemm_pv(const __hip_bfloat16* __restrict__ Ab, long sA,
             const __hip_bfloat16* __restrict__ Bb, long sB,
             __hip_bfloat16* __restrict__ C, int ldc, long sC)
{
    __shared__ __hip_bfloat16 As[64][32];
    __shared__ __hip_bfloat16 Bs[128][32];
    const int S = 1024;
    int h  = blockIdx.y;
    const __hip_bfloat16* A = Ab + (long)h * sA;
    const __hip_bfloat16* B = Bb + (long)h * sB;
    __hip_bfloat16* Ch = C + (long)h * sC;
    int m0 = blockIdx.x * 64;
    int tid  = threadIdx.x;
    int w    = tid >> 6, lane = tid & 63;
    int wm   = w >> 1,  wn   = w & 1;
    int lrow = lane >> 2;
    int lseg = (lane & 3) * 8;
    int fr   = lane & 15;
    int kg   = (lane >> 4) * 8;
    f32x4 acc[2][4] = {};
    for (int k0 = 0; k0 < S; k0 += 32) {
        gld_lds16(&A[(long)(m0 + w * 16 + lrow) * S + k0 + lseg], &As[w * 16][0]);
        #pragma unroll
        for (int i = 0; i < 2; ++i) {
            int r = w * 32 + i * 16;
            gld_lds16(&B[(long)(r + lrow) * S + k0 + lseg], &Bs[r][0]);
        }
        __syncthreads();
        bf16x8 af[2], bfr[4];
        #pragma unroll
        for (int m = 0; m < 2; ++m)
            af[m] = *(const bf16x8*)&As[wm * 32 + m * 16 + fr][kg];
        #pragma unroll
        for (int n = 0; n < 4; ++n)
            bfr[n] = *(const bf16x8*)&Bs[wn * 64 + n * 16 + fr][kg];
        #pragma unroll
        for (int m = 0; m < 2; ++m)
            #pragma unroll
            for (int n = 0; n < 4; ++n)
                acc[m][n] = __builtin_amdgcn_mfma_f32_16x16x32_bf16(af[m], bfr[n], acc[m][n], 0, 0, 0);
        __syncthreads();
    }
    int crow0 = (lane >> 4) * 4;
    #pragma unroll
    for (int m = 0; m < 2; ++m)
        #pragma unroll
        for (int n = 0; n < 4; ++n)
            #pragma unroll
            for (int r = 0; r < 4; ++r)
                Ch[(long)(m0 + wm * 32 + m * 16 + crow0 + r) * ldc
                   + wn * 64 + n * 16 + fr] = __float2bfloat16(acc[m][n][r]);
}

// ---------------- in-register split MFMA GEMM (QK^T): C = alpha * A * B^T ----------------
#define LP 40
__global__ __launch_bounds__(256)
void gemm_s(const float* __restrict__ A, int lda, long sA,
            const float* __restrict__ B, int ldb, long sB,
            float* __restrict__ C, int ldc, long sC,
            int Kd, float alpha)
{
    __shared__ short Ah[128][LP];
    __shared__ short Bh[128][LP];
    __shared__ short Al[128][LP];
    __shared__ short Bl[128][LP];
    long bz = blockIdx.z;
    A += bz * sA; B += bz * sB; C += bz * sC;
    int m0 = blockIdx.y * 128, n0 = blockIdx.x * 128;
    int tid  = threadIdx.x;
    int lane = tid & 63;
    int w    = tid >> 6;
    int wm   = w >> 1, wn = w & 1;
    int srow = tid >> 1;
    int scol = (tid & 1) * 16;
    int fr   = lane & 15;
    int kg   = (lane >> 4) * 8;
    f32x4 acc[4][4] = {};
    for (int k0 = 0; k0 < Kd; k0 += 32) {
        #pragma unroll
        for (int ab = 0; ab < 2; ++ab) {
            const float* src = ab ? (B + (long)(n0 + srow) * ldb + k0 + scol)
                                  : (A + (long)(m0 + srow) * lda + k0 + scol);
            short* dh = ab ? &Bh[srow][scol] : &Ah[srow][scol];
            short* dl = ab ? &Bl[srow][scol] : &Al[srow][scol];
            #pragma unroll
            for (int half = 0; half < 2; ++half) {
                float4 x0 = *reinterpret_cast<const float4*>(src + half * 8);
                float4 x1 = *reinterpret_cast<const float4*>(src + half * 8 + 4);
                float xs[8] = {x0.x, x0.y, x0.z, x0.w, x1.x, x1.y, x1.z, x1.w};
                bf16x8 hv, lv;
                #pragma unroll
                for (int j = 0; j < 8; ++j) {
                    short hb = f2bf(xs[j]);
                    hv[j] = hb;
                    lv[j] = f2bf(xs[j] - bf2f(hb));
                }
                *reinterpret_cast<bf16x8*>(dh + half * 8) = hv;
                *reinterpret_cast<bf16x8*>(dl + half * 8) = lv;
            }
        }
        __syncthreads();
        bf16x8 afh[4], bfh[4], afl[4], bfl[4];
        #pragma unroll
        for (int m = 0; m < 4; ++m) {
            afh[m] = *(const bf16x8*)&Ah[wm * 64 + m * 16 + fr][kg];
            afl[m] = *(const bf16x8*)&Al[wm * 64 + m * 16 + fr][kg];
        }
        #pragma unroll
        for (int n = 0; n < 4; ++n) {
            bfh[n] = *(const bf16x8*)&Bh[wn * 64 + n * 16 + fr][kg];
            bfl[n] = *(const bf16x8*)&Bl[wn * 64 + n * 16 + fr][kg];
        }
        #pragma unroll
        for (int m = 0; m < 4; ++m)
            #pragma unroll
            for (int n = 0; n < 4; ++n) {
                acc[m][n] = __builtin_amdgcn_mfma_f32_16x16x32_bf16(afh[m], bfh[n], acc[m][n], 0, 0, 0);
                acc[m][n] = __builtin_amdgcn_mfma_f32_16x16x32_bf16(afh[m], bfl[n], acc[m][n], 0, 0, 0);
                acc[m][n] = __builtin_amdgcn_mfma_f32_16x16x32_bf16(afl[m], bfh[n], acc[m][n], 0, 0, 0);
            }
        __syncthreads();
    }
    int crow0 = (lane >> 4) * 4;
    #pragma unroll
    for (int m = 0; m < 4; ++m)
        #pragma unroll
        for (int n = 0; n < 4; ++n)
            #pragma unroll
            for (int r = 0; r < 4; ++r)
                C[(long)(m0 + wm * 64 + m * 16 + crow0 + r) * ldc
                  + n0 + wn * 64 + n * 16 + fr] = alpha * acc[m][n][r];
}

// ---------------- f32 -> bf16 hi or lo part (n4 = n/4) ----------------
struct alignas(8) s4 { short a, b, c, d; };
template<bool LO>
__global__ __launch_bounds__(256)
void cvt_part(const float* __restrict__ x, short* __restrict__ y, long n4)
{
    long i = (long)blockIdx.x * 256 + threadIdx.x;
    long stride = (long)gridDim.x * 256;
    for (; i < n4; i += stride) {
        float4 v = reinterpret_cast<const float4*>(x)[i];
        float xs[4] = {v.x, v.y, v.z, v.w};
        s4 o;
        short* op = &o.a;
        #pragma unroll
        for (int j = 0; j < 4; ++j) {
            short hb = f2bf(xs[j]);
            op[j] = LO ? f2bf(xs[j] - bf2f(hb)) : hb;
        }
        reinterpret_cast<s4*>(y)[i] = o;
    }
}

// ---------------- f32 -> bf16 hi AND lo in one pass ----------------
__global__ __launch_bounds__(256)
void cvt_both(const float* __restrict__ x, short* __restrict__ yh,
              short* __restrict__ yl, long n4)
{
    long i = (long)blockIdx.x * 256 + threadIdx.x;
    long stride = (long)gridDim.x * 256;
    for (; i < n4; i += stride) {
        float4 v = reinterpret_cast<const float4*>(x)[i];
        float xs[4] = {v.x, v.y, v.z, v.w};
        s4 oh, ol;
        short* hp = &oh.a; short* lp = &ol.a;
        #pragma unroll
        for (int j = 0; j < 4; ++j) {
            short hb = f2bf(xs[j]);
            hp[j] = hb;
            lp[j] = f2bf(xs[j] - bf2f(hb));
        }
        reinterpret_cast<s4*>(yh)[i] = oh;
        reinterpret_cast<s4*>(yl)[i] = ol;
    }
}

// ---------------- RoPE in place on q,k [S][4096] ----------------
__global__ __launch_bounds__(256)
void rope_kernel(float* __restrict__ q, float* __restrict__ k, const int* __restrict__ pos)
{
    int i = blockIdx.x * 256 + threadIdx.x;
    if (i >= 1024 * 32 * 64) return;
    int d   = i & 63;
    int rem = i >> 6;
    int h   = rem & 31;
    int s   = rem >> 5;
    float p = (float)pos[s];
    float inv = exp2f(-(float)d * (13.287712379549449f / 64.0f));
    float ang = p * inv;
    float c = cosf(ang), sn = sinf(ang);
    long base = ((long)s * 4096) + h * 128 + d;
    float x1 = q[base], x2 = q[base + 64];
    q[base]      = x1 * c - x2 * sn;
    q[base + 64] = x2 * c + x1 * sn;
    x1 = k[base]; x2 = k[base + 64];
    k[base]      = x1 * c - x2 * sn;
    k[base + 64] = x2 * c + x1 * sn;
}

// ---------------- fused est + LayerNorm1: sc0 -> sc1, est ----------------
__global__ __launch_bounds__(256)
void est_ln1(const float* __restrict__ x, float* __restrict__ y,
             const float* __restrict__ sw, const float* __restrict__ sbias,
             float* __restrict__ est,
             const float* __restrict__ w, const float* __restrict__ b)
{
    long row = blockIdx.x;
    const float* xr = x + row * 1024;
    float* yr = y + row * 1024;
    __shared__ float sb[12];
    float v[4];
    float s = 0.f, ss = 0.f, dt = 0.f;
    #pragma unroll
    for (int i = 0; i < 4; ++i) {
        int c = threadIdx.x + i * 256;
        v[i] = xr[c];
        s += v[i]; ss += v[i] * v[i]; dt += v[i] * sw[c];
    }
    #pragma unroll
    for (int off = 32; off; off >>= 1) {
        s  += __shfl_down(s, off, 64);
        ss += __shfl_down(ss, off, 64);
        dt += __shfl_down(dt, off, 64);
    }
    int wid = threadIdx.x >> 6, lane = threadIdx.x & 63;
    if (!lane) { sb[wid] = s; sb[4 + wid] = ss; sb[8 + wid] = dt; }
    __syncthreads();
    s  = sb[0] + sb[1] + sb[2] + sb[3];
    ss = sb[4] + sb[5] + sb[6] + sb[7];
    if (threadIdx.x == 0) est[row] = sb[8] + sb[9] + sb[10] + sb[11] + sbias[0];
    float mean = s * (1.f / 1024.f);
    float var  = ss * (1.f / 1024.f) - mean * mean;
    float inv  = rsqrtf(var + 1e-5f);
    #pragma unroll
    for (int i = 0; i < 4; ++i) {
        int c = threadIdx.x + i * 256;
        yr[c] = (v[i] - mean) * inv * w[c] + b[c];
    }
}

// ---------------- causal depthwise conv + ReLU, register-tap ----------------
__global__ __launch_bounds__(256)
void conv_fast(const float* __restrict__ x, float* __restrict__ y,
               const float* __restrict__ cw, const float* __restrict__ cb,
               int layer, int h0)
{
    const int S = 1024;
    int h  = blockIdx.z;
    int hg = h0 + h;
    int q0 = blockIdx.y * 64;
    int k0 = blockIdx.x * 64;
    __shared__ float ws[63];
    if (threadIdx.x < 63) ws[threadIdx.x] = cw[(layer * 32 + hg) * 63 + threadIdx.x];
    __syncthreads();
    int c   = threadIdx.x & 63;
    int grp = threadIdx.x >> 6;
    int qb  = q0 + grp * 16;
    const float* xh = x + (long)h * S * S + k0 + c;
    float X[78];
    #pragma unroll
    for (int j = 0; j < 78; ++j) {
        int g = qb - 62 + j;
        X[j] = (g >= 0) ? xh[(long)g * S] : 0.f;
    }
    float wr[63];
    #pragma unroll
    for (int t = 0; t < 63; ++t) wr[t] = ws[t];
    float bias = cb[layer * 32 + hg];
    float* yh = y + (long)h * S * S + k0 + c;
    #pragma unroll
    for (int i = 0; i < 16; ++i) {
        float a0 = 0.f, a1 = 0.f, a2 = 0.f, a3 = 0.f;
        #pragma unroll
        for (int t = 0; t < 60; t += 4) {
            a0 += wr[t]     * X[i + t];
            a1 += wr[t + 1] * X[i + t + 1];
            a2 += wr[t + 2] * X[i + t + 2];
            a3 += wr[t + 3] * X[i + t + 3];
        }
        a0 += wr[60] * X[i + 60];
        a1 += wr[61] * X[i + 61];
        a2 += wr[62] * X[i + 62];
        float acc = bias + ((a0 + a1) + (a2 + a3));
        yh[(long)(qb + i) * S] = fmaxf(acc, 0.f);
    }
}

// ---------------- fused LayerNorm2 + mask + softmax + sigmoid gate -> bf16 p ----------------
__global__ __launch_bounds__(256)
void ln2_softmax(const float* __restrict__ x, __hip_bfloat16* __restrict__ pb,
                 const float* __restrict__ w, const float* __restrict__ b,
                 const float* __restrict__ mask, const float* __restrict__ est)
{
    const int S = 1024;
    long row = blockIdx.x;
    int q = (int)(row & (S - 1));
    const float* xr = x + row * 1024;
    const float* mrow = mask + (long)q * S;
    __shared__ float sb[8];
    float v[4];
    float s = 0.f, ss = 0.f;
    #pragma unroll
    for (int i = 0; i < 4; ++i) {
        int c = threadIdx.x + i * 256;
        v[i] = xr[c];
        s += v[i]; ss += v[i] * v[i];
    }
    #pragma unroll
    for (int off = 32; off; off >>= 1) {
        s  += __shfl_down(s, off, 64);
        ss += __shfl_down(ss, off, 64);
    }
    int wid = threadIdx.x >> 6, lane = threadIdx.x & 63;
    if (!lane) { sb[wid] = s; sb[4 + wid] = ss; }
    __syncthreads();
    s  = sb[0] + sb[1] + sb[2] + sb[3];
    ss = sb[4] + sb[5] + sb[6] + sb[7];
    float mean = s * (1.f / 1024.f);
    float var  = ss * (1.f / 1024.f) - mean * mean;
    float inv  = rsqrtf(var + 1e-5f);
    const float FMIN = -3.4028235e38f;
    float mx = FMIN;
    #pragma unroll
    for (int i = 0; i < 4; ++i) {
        int c = threadIdx.x + i * 256;
        float t = (v[i] - mean) * inv * w[c] + b[c] + mrow[c];
        t = fmaxf(t, FMIN);
        v[i] = t;
        mx = fmaxf(mx, t);
    }
    #pragma unroll
    for (int off = 32; off; off >>= 1) mx = fmaxf(mx, __shfl_down(mx, off, 64));
    __syncthreads();
    if (!lane) sb[wid] = mx;
    __syncthreads();
    mx = fmaxf(fmaxf(sb[0], sb[1]), fmaxf(sb[2], sb[3]));
    float s2 = 0.f;
    #pragma unroll
    for (int i = 0; i < 4; ++i) { v[i] = expf(v[i] - mx); s2 += v[i]; }
    #pragma unroll
    for (int off = 32; off; off >>= 1) s2 += __shfl_down(s2, off, 64);
    __syncthreads();
    if (!lane) sb[4 + wid] = s2;
    __syncthreads();
    s2 = sb[4] + sb[5] + sb[6] + sb[7];
    float e = est[row];
    float sc = (1.f / (1.f + expf(-e))) / s2;
    __hip_bfloat16* pr = pb + row * S;
    #pragma unroll
    for (int i = 0; i < 4; ++i) {
        int c = threadIdx.x + i * 256;
        pr[c] = __float2bfloat16(v[i] * sc);
    }
}

extern "C" void kernel_launch(void* const* d_in, const int* in_sizes, int n_in,
                              void* d_out, int out_size, void* d_ws, size_t ws_size,
                              hipStream_t stream) {
    const int S = 1024, H = 32, HID = 4096, DH = 128, DL = 64;

    const float* hs   = (const float*)d_in[0];
    const float* mask = (const float*)d_in[1];
    const int*   pos  = (const int*)d_in[2];
    const float* Wq   = (const float*)d_in[3];
    const float* Wk   = (const float*)d_in[4];
    const float* Wv   = (const float*)d_in[5];
    const float* Wo   = (const float*)d_in[6];
    const float* Wdq  = (const float*)d_in[7];
    const float* Wdk  = (const float*)d_in[8];
    const float* ln1w = (const float*)d_in[9];
    const float* ln1b = (const float*)d_in[10];
    const float* ln2w = (const float*)d_in[11];
    const float* ln2b = (const float*)d_in[12];
    const float* cw   = (const float*)d_in[13];
    const float* cb   = (const float*)d_in[14];
    const float* sw   = (const float*)d_in[15];
    const float* sbia = (const float*)d_in[16];
    float* out = (float*)d_out;

    // ---- workspace: minimize loop-live fixed footprint ----
    float* p   = (float*)d_ws;
    float* ql  = p; p += (long)H * S * DL;
    float* kl  = p; p += (long)H * S * DL;
    float* est = p; p += (long)H * S;
    short* hsH = (short*)p; p += (long)S * HID / 2;   // later aoH (PV out bf16)
    short* hsL = (short*)p; p += (long)S * HID / 2;   // later vT bf16 [H][128][1024]
    float* region = p;                                 // everything else
    float* qb  = region;
    float* kb  = qb + (long)S * HID;
    short* WbH = (short*)(kb + (long)S * HID);
    short* WbL = WbH + (long)HID * HID;
    short* aoH = hsH;
    short* vT  = hsL;

    long wsFloats     = (long)(ws_size / 4);
    long regionFloats = wsFloats - (region - (float*)d_ws);
    long perHead      = 2L * S * S;                    // sc0 + sc1 fp32
    int CH = (int)(regionFloats / perHead);
    if (CH > H) CH = H;
    if (CH < 1) CH = 1;
    int iters = (H + CH - 1) / CH;
    CH = (H + iters - 1) / iters;                      // even chunks
    float* sc0 = region;
    float* sc1 = sc0 + (long)CH * S * S;
    __hip_bfloat16* pb = (__hip_bfloat16*)sc1;         // alias: sc1 dead after conv l2

    dim3 blk(256);
    dim3 gP(HID / 128, S / 64, 1);                     // 64x128 tiles, 512 blocks
    long n4_hs = (long)S * HID / 4, n4_W = (long)HID * HID / 4;

    // hs -> hi/lo bf16
    cvt_both<<<2048, blk, 0, stream>>>(hs, hsH, hsL, n4_hs);

    // ---- Q projection: single-pass 3-term, 64x128 tiles, no atomics ----
    cvt_both<<<2048, blk, 0, stream>>>(Wq, WbH, WbL, n4_W);
    gemm64<0, true><<<gP, blk, 0, stream>>>(
        (__hip_bfloat16*)hsH, (__hip_bfloat16*)hsL, HID,
        (__hip_bfloat16*)WbH, (__hip_bfloat16*)WbL, HID,
        qb, HID, HID, 1.f);

    // ---- K projection ----
    cvt_both<<<2048, blk, 0, stream>>>(Wk, WbH, WbL, n4_W);
    gemm64<0, true><<<gP, blk, 0, stream>>>(
        (__hip_bfloat16*)hsH, (__hip_bfloat16*)hsL, HID,
        (__hip_bfloat16*)WbH, (__hip_bfloat16*)WbL, HID,
        kb, HID, HID, 1.f);

    // ---- V projection: hi-only, writes vT bf16 [H][128][1024] (transposed epilogue) ----
    cvt_part<false><<<2048, blk, 0, stream>>>(Wv, WbH, n4_W);
    gemm64<2, false><<<gP, blk, 0, stream>>>(
        (__hip_bfloat16*)hsH, (__hip_bfloat16*)hsH, HID,
        (__hip_bfloat16*)WbH, (__hip_bfloat16*)WbH, HID,
        vT, S, HID, 1.f);

    rope_kernel<<<(S * H * 64 + 255) / 256, blk, 0, stream>>>(qb, kb, pos);

    // low-rank down-proj (fp32 VALU, exact)
    gemm_f32<true><<<dim3(1, S / 64, H), blk, 0, stream>>>(qb, HID, 128, Wdq, DH, 0, ql, DL, (long)S * DL, S, DL, DH, 1.f);
    gemm_f32<true><<<dim3(1, S / 64, H), blk, 0, stream>>>(kb, HID, 128, Wdk, DH, 0, kl, DL, (long)S * DL, S, DL, DH, 1.f);
    // qb/kb/WbH/WbL now dead -> region becomes the score area

    for (int c0 = 0; c0 < H; c0 += CH) {
        int ch = (c0 + CH <= H) ? CH : (H - c0);
        gemm_s<<<dim3(S / 128, S / 128, ch), blk, 0, stream>>>(
            ql + (long)c0 * S * DL, DL, (long)S * DL,
            kl + (long)c0 * S * DL, DL, (long)S * DL,
            sc0, S, (long)S * S, DL, 0.125f);
        est_ln1<<<ch * S, blk, 0, stream>>>(sc0, sc1, sw, sbia, est + (long)c0 * S, ln1w, ln1b);
        conv_fast<<<dim3(16, 16, ch), blk, 0, stream>>>(sc1, sc0, cw, cb, 0, c0);
        conv_fast<<<dim3(16, 16, ch), blk, 0, stream>>>(sc0, sc1, cw, cb, 1, c0);
        conv_fast<<<dim3(16, 16, ch), blk, 0, stream>>>(sc1, sc0, cw, cb, 2, c0);
        ln2_softmax<<<ch * S, blk, 0, stream>>>(sc0, pb, ln2w, ln2b, mask, est + (long)c0 * S);
        gemm_pv<<<dim3(S / 64, ch), blk, 0, stream>>>(
            pb, (long)S * S,
            (__hip_bfloat16*)(vT + (long)c0 * DH * S), (long)DH * S,
            (__hip_bfloat16*)(aoH + (long)c0 * 128), HID, 128);
    }

    // ---- final: out = aoH @ Wo^T (hi-only, 64x128 tiles, direct store) ----
    short* WoH = (short*)region;   // scores dead after last PV
    cvt_part<false><<<2048, blk, 0, stream>>>(Wo, WoH, n4_W);
    gemm64<0, false><<<gP, blk, 0, stream>>>(
        (__hip_bfloat16*)aoH, (__hip_bfloat16*)aoH, HID,
        (__hip_bfloat16*)WoH, (__hip_bfloat16*)WoH, HID,
        out, HID, HID, 1.f);
}